// Round 6
// baseline (8463.453 us; speedup 1.0000x reference)
//
#include <hip/hip_runtime.h>
#include <hip/hip_bf16.h>

#define N_NODES 10000
#define N_EDGES 160000
#define N_GRAPHS 64
#define NK 5
#define EPS 1e-5f
#define EPB 128          // edges per block
#define JP 768           // padded edge-MLP width (642 -> 768), pads are true zeros
#define CHC 128          // cols per chunk
#define NCH 6            // JP / CHC
#define PSTRIDE 1536     // Pab row stride: [Pa 768 | Pb 768]

__device__ __forceinline__ float silu(float x) { return x / (1.0f + __expf(-x)); }
__device__ __forceinline__ float4 f4fma(float s, float4 w, float4 a) {
    a.x = fmaf(s, w.x, a.x); a.y = fmaf(s, w.y, a.y);
    a.z = fmaf(s, w.z, a.z); a.w = fmaf(s, w.w, a.w);
    return a;
}
__device__ __forceinline__ float wave_sum64(float v) {
    #pragma unroll
    for (int off = 32; off > 0; off >>= 1) v += __shfl_xor(v, off, 64);
    return v;
}

// ---------------- embedding ----------------
__global__ __launch_bounds__(128) void k_embed(const int* __restrict__ atomids,
                                               const float* __restrict__ emb_w,
                                               float* __restrict__ feats_all) {
    int n = blockIdx.x, tid = threadIdx.x;
    feats_all[(size_t)n * 768 + tid] = emb_w[(size_t)atomids[n] * 128 + tid];
}

// ---------------- fourier table, transposed: feT[k][e] ----------------
__global__ __launch_bounds__(64) void k_fe(const float* __restrict__ coords,
                                           const int* __restrict__ eidx,
                                           float* __restrict__ feT) {
    int e = blockIdx.x * 64 + threadIdx.x;
    if (e >= N_EDGES) return;
    int s = eidx[e], d = eidx[N_EDGES + e];
    float dx = coords[s * 3 + 0] - coords[d * 3 + 0];
    float dy = coords[s * 3 + 1] - coords[d * 3 + 1];
    float dz = coords[s * 3 + 2] - coords[d * 3 + 2];
    float d2 = dx * dx + dy * dy + dz * dz;
    float sc = 1.0f;
    #pragma unroll
    for (int i = 0; i < 32; ++i) {
        float x = d2 * sc;
        feT[(size_t)i * N_EDGES + e] = sinf(x);
        feT[(size_t)(32 + i) * N_EDGES + e] = cosf(x);
        sc *= 0.5f;
    }
    feT[(size_t)64 * N_EDGES + e] = d2;
}

// ---------------- W1ab prestage: [128][1536] = [W1a | 0 | W1b | 0] ----------------
__global__ __launch_bounds__(256) void k_w1ab(const float* __restrict__ W1,  // [321][642]
                                              float* __restrict__ W1ab) {
    int idx = blockIdx.x * 256 + threadIdx.x;
    if (idx >= 128 * 1536) return;
    int r = idx / 1536;
    int j = idx - r * 1536;
    float v = 0.f;
    if (j < 642) v = W1[(size_t)r * 642 + j];
    else if (j >= 768 && j < 1410) v = W1[(size_t)(128 + r) * 642 + (j - 768)];
    W1ab[idx] = v;
}

// ---------------- batched padded edge-weight prestage (all 5 layers, one launch) ----------------
__global__ __launch_bounds__(256) void k_wpre5(const float* __restrict__ eW1,  // [5][321][642]
                                               const float* __restrict__ eb1,  // [5][642]
                                               const float* __restrict__ eW2,  // [5][642][32]
                                               float* __restrict__ W1cp5,      // [5][65][768]
                                               float* __restrict__ b1p5,       // [5][768]
                                               float* __restrict__ W2p5) {     // [5][768][32]
    int k = blockIdx.y;
    const float* W1 = eW1 + (size_t)k * 321 * 642;
    const float* b1 = eb1 + (size_t)k * 642;
    const float* W2 = eW2 + (size_t)k * 642 * 32;
    float* W1cp = W1cp5 + (size_t)k * 65 * 768;
    float* b1p  = b1p5 + (size_t)k * 768;
    float* W2p  = W2p5 + (size_t)k * 768 * 32;
    int idx = blockIdx.x * 256 + threadIdx.x;
    if (idx < 65 * 768) {
        int r = idx / 768, j = idx - r * 768;
        W1cp[idx] = (j < 642) ? W1[(size_t)(256 + r) * 642 + j] : 0.f;
    } else if (idx < 65 * 768 + 768) {
        int j = idx - 65 * 768;
        b1p[j] = (j < 642) ? b1[j] : 0.f;
    } else if (idx < 65 * 768 + 768 + 768 * 32) {
        int t = idx - (65 * 768 + 768);
        int j = t >> 5, c = t & 31;
        W2p[t] = (j < 642) ? W2[(size_t)j * 32 + c] : 0.f;
    }
}

// ---------------- fp32 GEMM: C = act(actA(A)[M][K] @ B[K][N] + bias) ----------------
__global__ __launch_bounds__(256) void k_gemm(const float* __restrict__ A, int lda,
                                              const float* __restrict__ B, int ldb,
                                              const float* __restrict__ bias,
                                              float* __restrict__ C, int ldc,
                                              int M, int N, int K, int siluA, int siluOut) {
    __shared__ float As[32 * 132];
    __shared__ float Bs[32 * 132];
    const int tid = threadIdx.x;
    const int m0 = blockIdx.x * 128, n0 = blockIdx.y * 128;
    const int tm = tid >> 4, tn = tid & 15;

    float4 acc[8][2];
    #pragma unroll
    for (int r = 0; r < 8; ++r) { acc[r][0] = make_float4(0,0,0,0); acc[r][1] = make_float4(0,0,0,0); }

    for (int kc = 0; kc < K; kc += 32) {
        #pragma unroll
        for (int i = 0; i < 4; ++i) {
            int idx = tid + i * 256;
            int m = idx >> 3, kq = idx & 7;
            int gm = m0 + m;
            int cm = (gm < M) ? gm : (M - 1);
            float4 a = *(const float4*)(A + (size_t)cm * lda + kc + 4 * kq);
            if (gm >= M) a = make_float4(0,0,0,0);
            if (siluA) { a.x = silu(a.x); a.y = silu(a.y); a.z = silu(a.z); a.w = silu(a.w); }
            As[(4 * kq + 0) * 132 + m] = a.x;
            As[(4 * kq + 1) * 132 + m] = a.y;
            As[(4 * kq + 2) * 132 + m] = a.z;
            As[(4 * kq + 3) * 132 + m] = a.w;
        }
        #pragma unroll
        for (int i = 0; i < 4; ++i) {
            int idx = tid + i * 256;
            int r = idx >> 5, cq = idx & 31;
            int gn = n0 + 4 * cq;
            float4 b = make_float4(0,0,0,0);
            if (gn < N) b = *(const float4*)(B + (size_t)(kc + r) * ldb + gn);
            *(float4*)&Bs[r * 132 + 4 * cq] = b;
        }
        __syncthreads();
        #pragma unroll 4
        for (int kk = 0; kk < 32; ++kk) {
            float4 a0 = *(const float4*)&As[kk * 132 + 8 * tm];
            float4 a1 = *(const float4*)&As[kk * 132 + 8 * tm + 4];
            float4 b0 = *(const float4*)&Bs[kk * 132 + 4 * tn];
            float4 b1 = *(const float4*)&Bs[kk * 132 + 64 + 4 * tn];
            acc[0][0] = f4fma(a0.x, b0, acc[0][0]); acc[0][1] = f4fma(a0.x, b1, acc[0][1]);
            acc[1][0] = f4fma(a0.y, b0, acc[1][0]); acc[1][1] = f4fma(a0.y, b1, acc[1][1]);
            acc[2][0] = f4fma(a0.z, b0, acc[2][0]); acc[2][1] = f4fma(a0.z, b1, acc[2][1]);
            acc[3][0] = f4fma(a0.w, b0, acc[3][0]); acc[3][1] = f4fma(a0.w, b1, acc[3][1]);
            acc[4][0] = f4fma(a1.x, b0, acc[4][0]); acc[4][1] = f4fma(a1.x, b1, acc[4][1]);
            acc[5][0] = f4fma(a1.y, b0, acc[5][0]); acc[5][1] = f4fma(a1.y, b1, acc[5][1]);
            acc[6][0] = f4fma(a1.z, b0, acc[6][0]); acc[6][1] = f4fma(a1.z, b1, acc[6][1]);
            acc[7][0] = f4fma(a1.w, b0, acc[7][0]); acc[7][1] = f4fma(a1.w, b1, acc[7][1]);
        }
        __syncthreads();
    }

    const int gnl = n0 + 4 * tn, gnh = n0 + 64 + 4 * tn;
    #pragma unroll
    for (int r = 0; r < 8; ++r) {
        int gm = m0 + 8 * tm + r;
        if (gm >= M) continue;
        float4 v0 = acc[r][0], v1 = acc[r][1];
        if (gnl < N) {
            if (bias) { v0.x += bias[gnl+0]; v0.y += bias[gnl+1]; v0.z += bias[gnl+2]; v0.w += bias[gnl+3]; }
            if (siluOut) { v0.x = silu(v0.x); v0.y = silu(v0.y); v0.z = silu(v0.z); v0.w = silu(v0.w); }
            *(float4*)&C[(size_t)gm * ldc + gnl] = v0;
        }
        if (gnh < N) {
            if (bias) { v1.x += bias[gnh+0]; v1.y += bias[gnh+1]; v1.z += bias[gnh+2]; v1.w += bias[gnh+3]; }
            if (siluOut) { v1.x = silu(v1.x); v1.y = silu(v1.y); v1.z = silu(v1.z); v1.w = silu(v1.w); }
            *(float4*)&C[(size_t)gm * ldc + gnh] = v1;
        }
    }
}

// ---------------- fused edge kernel, wave-aligned 8x8 micro + k-split phase 2 ----------------
// Phase1: thread (et,cg) owns 8 edges x 8 cols; per-wave address sets span 64 floats -> 2-way (free).
// Phase2: thread (eg,cq,ks) owns 8 edges x 8 cols, kk = 4t+ks (k-split 4); accm[8][8] across kernel;
//         4-round LDS reduction into m2s (overlays dead feTs), then LN + scatter.
__global__ __launch_bounds__(256, 2) void k_edge(const float* __restrict__ feT,   // [65][N_EDGES]
                                                 const float* __restrict__ Pab,   // [N_NODES][1536]
                                                 const int* __restrict__ eidx,
                                                 const float* __restrict__ W1cp,  // [65][768]
                                                 const float* __restrict__ b1p,   // [768]
                                                 const float* __restrict__ W2p,   // [768][32]
                                                 const float* __restrict__ b2,
                                                 const float* __restrict__ eng,
                                                 const float* __restrict__ enb,
                                                 float* __restrict__ S,
                                                 float* __restrict__ cnt) {
    __shared__ float feTs[65 * 132];   // [k][e] 34320 B ; reused as m2s[128][36] at epilogue
    __shared__ float W1s[33 * 132];    // 17424 B (half-staged)
    __shared__ float Zs[32 * 132];     // [j][e] 16896 B
    __shared__ float W2s[32 * 36];     //  4608 B
    __shared__ int dsi[EPB], ssi[EPB]; //  1024 B
    __shared__ float cpar[96];         //   384 B  -> 74656 B total

    const int tid = threadIdx.x;
    const int w = tid >> 6, lane = tid & 63;
    const int eb = blockIdx.x * EPB;
    // phase-1 mapping (8 et, 8 cg per wave -> 2-way LDS max)
    const int et = (lane & 7) | ((w & 1) << 3);          // 0..15, edges 8*et..
    const int cg = ((lane >> 3) & 7) | ((w >> 1) << 3);  // 0..15, cols 8*cg..
    // phase-2 mapping
    const int eg = (lane & 7) | ((w >> 1) << 3);         // 0..15, edges 8*eg..
    const int cq = (lane >> 3) & 3;                      // 0..3,  cols 8*cq..
    const int ks = ((lane >> 5) & 1) | ((w & 1) << 1);   // 0..3,  kk = 4t+ks

    if (tid < EPB) {
        ssi[tid] = eidx[eb + tid];
        dsi[tid] = eidx[N_EDGES + eb + tid];
    }
    if (tid < 32) cpar[tid] = b2[tid];
    else if (tid < 64) cpar[tid] = eng[tid - 32];
    else if (tid < 96) cpar[tid] = enb[tid - 64];
    for (int idx = tid; idx < 65 * 32; idx += 256) {
        int k = idx >> 5, q = idx & 31;
        *(float4*)&feTs[k * 132 + 4 * q] = *(const float4*)(feT + (size_t)k * N_EDGES + eb + 4 * q);
    }
    __syncthreads();

    int dsr[8], ssr[8];
    #pragma unroll
    for (int i = 0; i < 8; ++i) { dsr[i] = dsi[8 * et + i]; ssr[i] = ssi[8 * et + i]; }

    float accm[8][8];
    #pragma unroll
    for (int i = 0; i < 8; ++i)
        #pragma unroll
        for (int c = 0; c < 8; ++c) accm[i][c] = 0.f;

    for (int ch = 0; ch < NCH; ++ch) {
        const int jc = ch * CHC;

        // ---- qa init: gathered Pa/Pb + b1 ----
        float qa[8][8];
        {
            float4 blo = *(const float4*)(b1p + jc + 8 * cg);
            float4 bhi = *(const float4*)(b1p + jc + 8 * cg + 4);
            #pragma unroll
            for (int i = 0; i < 8; ++i) {
                const float* pr = Pab + (size_t)dsr[i] * PSTRIDE + jc + 8 * cg;
                const float* qr = Pab + (size_t)ssr[i] * PSTRIDE + JP + jc + 8 * cg;
                float4 a0 = *(const float4*)pr;
                float4 a1 = *(const float4*)(pr + 4);
                float4 c0 = *(const float4*)qr;
                float4 c1 = *(const float4*)(qr + 4);
                qa[i][0] = a0.x + c0.x + blo.x; qa[i][1] = a0.y + c0.y + blo.y;
                qa[i][2] = a0.z + c0.z + blo.z; qa[i][3] = a0.w + c0.w + blo.w;
                qa[i][4] = a1.x + c1.x + bhi.x; qa[i][5] = a1.y + c1.y + bhi.y;
                qa[i][6] = a1.z + c1.z + bhi.z; qa[i][7] = a1.w + c1.w + bhi.w;
            }
        }

        // ---- stage W1s rows 0..32 ----
        #pragma unroll
        for (int i = 0; i < 5; ++i) {
            int idx = tid + i * 256;
            if (idx < 33 * 32) {
                int r = idx >> 5, q = idx & 31;
                *(float4*)&W1s[r * 132 + 4 * q] = *(const float4*)(W1cp + (size_t)r * 768 + jc + 4 * q);
            }
        }
        __syncthreads();
        for (int kk = 0; kk < 33; ++kk) {
            float4 f0 = *(const float4*)&feTs[kk * 132 + 8 * et];
            float4 f1 = *(const float4*)&feTs[kk * 132 + 8 * et + 4];
            float4 w0 = *(const float4*)&W1s[kk * 132 + 8 * cg];
            float4 w1 = *(const float4*)&W1s[kk * 132 + 8 * cg + 4];
            float fv[8] = {f0.x, f0.y, f0.z, f0.w, f1.x, f1.y, f1.z, f1.w};
            float wv[8] = {w0.x, w0.y, w0.z, w0.w, w1.x, w1.y, w1.z, w1.w};
            #pragma unroll
            for (int i = 0; i < 8; ++i)
                #pragma unroll
                for (int c = 0; c < 8; ++c) qa[i][c] = fmaf(fv[i], wv[c], qa[i][c]);
        }
        __syncthreads();
        // ---- stage W1s rows 33..64 ----
        #pragma unroll
        for (int i = 0; i < 4; ++i) {
            int idx = tid + i * 256;
            if (idx < 32 * 32) {
                int r = idx >> 5, q = idx & 31;
                *(float4*)&W1s[r * 132 + 4 * q] = *(const float4*)(W1cp + (size_t)(33 + r) * 768 + jc + 4 * q);
            }
        }
        __syncthreads();
        for (int kk = 0; kk < 32; ++kk) {
            float4 f0 = *(const float4*)&feTs[(33 + kk) * 132 + 8 * et];
            float4 f1 = *(const float4*)&feTs[(33 + kk) * 132 + 8 * et + 4];
            float4 w0 = *(const float4*)&W1s[kk * 132 + 8 * cg];
            float4 w1 = *(const float4*)&W1s[kk * 132 + 8 * cg + 4];
            float fv[8] = {f0.x, f0.y, f0.z, f0.w, f1.x, f1.y, f1.z, f1.w};
            float wv[8] = {w0.x, w0.y, w0.z, w0.w, w1.x, w1.y, w1.z, w1.w};
            #pragma unroll
            for (int i = 0; i < 8; ++i)
                #pragma unroll
                for (int c = 0; c < 8; ++c) qa[i][c] = fmaf(fv[i], wv[c], qa[i][c]);
        }

        // ---- z = silu(qa) ----
        #pragma unroll
        for (int i = 0; i < 8; ++i)
            #pragma unroll
            for (int c = 0; c < 8; ++c) qa[i][c] = silu(qa[i][c]);

        // ---- phase 2: 4 sub-passes of 32 j ----
        #pragma unroll
        for (int p = 0; p < 4; ++p) {
            __syncthreads();
            if ((cg >> 2) == p) {
                int jl = 8 * (cg & 3);
                #pragma unroll
                for (int jj = 0; jj < 8; ++jj) {
                    *(float4*)&Zs[(jl + jj) * 132 + 8 * et]     = make_float4(qa[0][jj], qa[1][jj], qa[2][jj], qa[3][jj]);
                    *(float4*)&Zs[(jl + jj) * 132 + 8 * et + 4] = make_float4(qa[4][jj], qa[5][jj], qa[6][jj], qa[7][jj]);
                }
            }
            {   // stage W2s rows for this pass
                int r = tid >> 3, q = tid & 7;
                *(float4*)&W2s[r * 36 + 4 * q] = *(const float4*)(W2p + (size_t)(jc + 32 * p + r) * 32 + 4 * q);
            }
            __syncthreads();
            #pragma unroll
            for (int t = 0; t < 8; ++t) {
                int kk = 4 * t + ks;
                float4 z0 = *(const float4*)&Zs[kk * 132 + 8 * eg];
                float4 z1 = *(const float4*)&Zs[kk * 132 + 8 * eg + 4];
                float4 w0 = *(const float4*)&W2s[kk * 36 + 8 * cq];
                float4 w1 = *(const float4*)&W2s[kk * 36 + 8 * cq + 4];
                float zv[8] = {z0.x, z0.y, z0.z, z0.w, z1.x, z1.y, z1.z, z1.w};
                float wv[8] = {w0.x, w0.y, w0.z, w0.w, w1.x, w1.y, w1.z, w1.w};
                #pragma unroll
                for (int i = 0; i < 8; ++i)
                    #pragma unroll
                    for (int c = 0; c < 8; ++c) accm[i][c] = fmaf(zv[i], wv[c], accm[i][c]);
            }
        }
    }

    // ---- ks reduction into m2s (overlays feTs) ----
    float* m2s = feTs;   // [128][36]
    #pragma unroll
    for (int r = 0; r < 4; ++r) {
        __syncthreads();
        if (ks == r) {
            #pragma unroll
            for (int i = 0; i < 8; ++i) {
                int base = (8 * eg + i) * 36 + 8 * cq;
                if (r == 0) {
                    *(float4*)&m2s[base]     = make_float4(accm[i][0], accm[i][1], accm[i][2], accm[i][3]);
                    *(float4*)&m2s[base + 4] = make_float4(accm[i][4], accm[i][5], accm[i][6], accm[i][7]);
                } else {
                    float4 v0 = *(const float4*)&m2s[base];
                    float4 v1 = *(const float4*)&m2s[base + 4];
                    v0.x += accm[i][0]; v0.y += accm[i][1]; v0.z += accm[i][2]; v0.w += accm[i][3];
                    v1.x += accm[i][4]; v1.y += accm[i][5]; v1.z += accm[i][6]; v1.w += accm[i][7];
                    *(float4*)&m2s[base]     = v0;
                    *(float4*)&m2s[base + 4] = v1;
                }
            }
        }
    }
    __syncthreads();

    // ---- epilogue: m2 = silu(raw + b2), LN, scatter ----
    if (tid < EPB) {
        float s = 0.f, ss = 0.f;
        float v[32];
        #pragma unroll
        for (int c = 0; c < 32; ++c) {
            float x = silu(m2s[tid * 36 + c] + cpar[c]);
            v[c] = x; s += x; ss += x * x;
        }
        float mean = s * 0.03125f;
        float var = ss * 0.03125f - mean * mean;
        float rstd = 1.0f / sqrtf(var + EPS);
        int d = dsi[tid];
        float* Sp = S + (size_t)d * 32;
        #pragma unroll
        for (int c = 0; c < 32; ++c) {
            float y = (v[c] - mean) * rstd * cpar[32 + c] + cpar[64 + c];
            atomicAdd(&Sp[c], y);
        }
        atomicAdd(&cnt[d], 1.0f);
    }
}

// ---------------- node prep: H0 = [LN(feats) | LN(S/cnt)] ----------------
__global__ __launch_bounds__(128) void k_prep(const float* __restrict__ featsk,
                                              const float* __restrict__ S,
                                              const float* __restrict__ cnt,
                                              const float* __restrict__ nn1g,
                                              const float* __restrict__ nn1b,
                                              const float* __restrict__ eng,
                                              const float* __restrict__ enb,
                                              float* __restrict__ H0) {
    int n = blockIdx.x, tid = threadIdx.x;
    __shared__ float red[4];
    float x = featsk[(size_t)n * 768 + tid];
    float s = wave_sum64(x), ss = wave_sum64(x * x);
    if ((tid & 63) == 0) { red[(tid >> 6) * 2] = s; red[(tid >> 6) * 2 + 1] = ss; }
    __syncthreads();
    float S1 = red[0] + red[2], S2 = red[1] + red[3];
    float mean = S1 * (1.0f / 128.0f);
    float var = S2 * (1.0f / 128.0f) - mean * mean;
    float rstd = 1.0f / sqrtf(var + EPS);
    H0[(size_t)n * 160 + tid] = (x - mean) * rstd * nn1g[tid] + nn1b[tid];
    if (tid < 32) {
        float inv = 1.0f / fmaxf(cnt[n], 1.0f);
        float v = S[(size_t)n * 32 + tid] * inv;
        float s2 = v, q2 = v * v;
        #pragma unroll
        for (int off = 16; off > 0; off >>= 1) {
            s2 += __shfl_xor(s2, off, 64);
            q2 += __shfl_xor(q2, off, 64);
        }
        float m2 = s2 * (1.0f / 32.0f);
        float va = q2 * (1.0f / 32.0f) - m2 * m2;
        float rs = 1.0f / sqrtf(va + EPS);
        H0[(size_t)n * 160 + 128 + tid] = (v - m2) * rs * eng[tid] + enb[tid];
    }
}

// ---------------- LN + residual ----------------
__global__ __launch_bounds__(128) void k_ln_res(const float* __restrict__ H2,
                                                float* __restrict__ feats_all, int k,
                                                const float* __restrict__ g,
                                                const float* __restrict__ b) {
    int n = blockIdx.x, tid = threadIdx.x;
    __shared__ float red[4];
    float x = H2[(size_t)n * 128 + tid];
    float s = wave_sum64(x), ss = wave_sum64(x * x);
    if ((tid & 63) == 0) { red[(tid >> 6) * 2] = s; red[(tid >> 6) * 2 + 1] = ss; }
    __syncthreads();
    float S1 = red[0] + red[2], S2 = red[1] + red[3];
    float mean = S1 * (1.0f / 128.0f);
    float var = S2 * (1.0f / 128.0f) - mean * mean;
    float rstd = 1.0f / sqrtf(var + EPS);
    float v = (x - mean) * rstd * g[tid] + b[tid];
    float f = feats_all[(size_t)n * 768 + k * 128 + tid];
    feats_all[(size_t)n * 768 + (k + 1) * 128 + tid] = f + v;
}

// ---------------- graph pooling (batch sorted -> run-length accum) ----------------
__global__ __launch_bounds__(256) void k_pool(const float* __restrict__ F,
                                              const int* __restrict__ batch,
                                              float* __restrict__ G,
                                              float* __restrict__ cntg) {
    __shared__ int bL[32];
    int b0 = blockIdx.x * 32;
    int tid = threadIdx.x;
    int nmax = min(32, N_NODES - b0);
    if (nmax <= 0) return;
    if (tid < nmax) bL[tid] = batch[b0 + tid];
    __syncthreads();
    float accv = 0.f;
    int cur = -1;
    for (int i = 0; i < nmax; ++i) {
        int g = bL[i];
        if (g != cur) {
            if (cur >= 0) atomicAdd(&G[(size_t)cur * 256 + tid], accv);
            cur = g; accv = 0.f;
        }
        accv += F[(size_t)(b0 + i) * 256 + tid];
    }
    if (cur >= 0) atomicAdd(&G[(size_t)cur * 256 + tid], accv);
    if (tid == 0)
        for (int i = 0; i < nmax; ++i) atomicAdd(&cntg[bL[i]], 1.0f);
}

// ---------------- per-graph MLP head ----------------
__global__ __launch_bounds__(256) void k_graph(const float* __restrict__ G,
                                               const float* __restrict__ cntg,
                                               const float* __restrict__ g1W,
                                               const float* __restrict__ g1b,
                                               const float* __restrict__ g2W,
                                               const float* __restrict__ g2b,
                                               const float* __restrict__ g3W,
                                               const float* __restrict__ g3b,
                                               float* __restrict__ out) {
    __shared__ float X[256], Y[256], red[4];
    int g = blockIdx.x, tid = threadIdx.x;
    float inv = 1.0f / fmaxf(cntg[g], 1.0f);
    X[tid] = G[(size_t)g * 256 + tid] * inv;
    __syncthreads();
    float a = g1b[tid];
    for (int j = 0; j < 256; ++j) a = fmaf(X[j], g1W[(size_t)j * 256 + tid], a);
    Y[tid] = silu(a);
    __syncthreads();
    a = g2b[tid];
    for (int j = 0; j < 256; ++j) a = fmaf(Y[j], g2W[(size_t)j * 256 + tid], a);
    float z = silu(a);
    float p = z * g3W[tid];
    p = wave_sum64(p);
    if ((tid & 63) == 0) red[tid >> 6] = p;
    __syncthreads();
    if (tid == 0) out[g] = red[0] + red[1] + red[2] + red[3] + g3b[0];
}

extern "C" void kernel_launch(void* const* d_in, const int* in_sizes, int n_in,
                              void* d_out, int out_size, void* d_ws, size_t ws_size,
                              hipStream_t stream) {
    const int*   atomids = (const int*)d_in[0];
    const float* coords  = (const float*)d_in[1];
    const int*   eidx    = (const int*)d_in[2];
    const int*   batch   = (const int*)d_in[3];
    const float* emb_w   = (const float*)d_in[4];
    const float* eW1     = (const float*)d_in[5];
    const float* eb1     = (const float*)d_in[6];
    const float* eW2     = (const float*)d_in[7];
    const float* eb2     = (const float*)d_in[8];
    const float* en_g    = (const float*)d_in[9];
    const float* en_b    = (const float*)d_in[10];
    const float* nn1_g   = (const float*)d_in[11];
    const float* nn1_b   = (const float*)d_in[12];
    const float* nW1     = (const float*)d_in[13];
    const float* nb1     = (const float*)d_in[14];
    const float* nW2     = (const float*)d_in[15];
    const float* nb2     = (const float*)d_in[16];
    const float* nn2_g   = (const float*)d_in[17];
    const float* nn2_b   = (const float*)d_in[18];
    const float* f1W     = (const float*)d_in[19];
    const float* f1b     = (const float*)d_in[20];
    const float* f2W     = (const float*)d_in[21];
    const float* f2b     = (const float*)d_in[22];
    const float* f3W     = (const float*)d_in[23];
    const float* f3b     = (const float*)d_in[24];
    const float* g1W     = (const float*)d_in[25];
    const float* g1b     = (const float*)d_in[26];
    const float* g2W     = (const float*)d_in[27];
    const float* g2b     = (const float*)d_in[28];
    const float* g3W     = (const float*)d_in[29];
    const float* g3b     = (const float*)d_in[30];
    float* out = (float*)d_out;

    float* ws = (float*)d_ws;
    // layout (float indices, 16B-aligned); total ~34.36M floats ~= 137.4 MB
    float* feats_all = ws;                        // [10000][768]
    float* feT   = ws + 7680000;                  // [65][160000]
    float* Pab   = ws + 18080000;                 // [10000][1536]
    float* S     = ws + 33440000;                 // [10000][32]
    float* cnt   = ws + 33760000;                 // [10000]
    float* W1ab  = ws + 33770000;                 // [128][1536]
    float* W1cp5 = ws + 33966608;                 // [5][65][768]
    float* b1p5  = ws + 34216208;                 // [5][768]
    float* W2p5  = ws + 34220048;                 // [5][768][32]
    float* G     = ws + 34342928;                 // [64][256]
    float* cntg  = ws + 34359312;                 // [64]
    // node-phase temporaries overlay Pab (dead between phases)
    float* H0 = Pab;                              // [10000][160]
    float* H1 = Pab + 1600000;                    // [10000][256]
    float* H2 = Pab + 4160000;                    // [10000][128]
    float* F1 = Pab;                              // [10000][256]
    float* F2 = Pab + 2560000;                    // [10000][256]
    float* F3 = Pab + 5120000;                    // [10000][256]

    k_embed<<<N_NODES, 128, 0, stream>>>(atomids, emb_w, feats_all);
    k_fe<<<N_EDGES / 64, 64, 0, stream>>>(coords, eidx, feT);
    k_wpre5<<<dim3(294, 5), 256, 0, stream>>>(eW1, eb1, eW2, W1cp5, b1p5, W2p5);

    for (int k = 0; k < NK; ++k) {
        const float* eW1k = eW1 + (size_t)k * 321 * 642;
        const float* eb2k = eb2 + (size_t)k * 32;
        const float* engk = en_g + (size_t)k * 32;
        const float* enbk = en_b + (size_t)k * 32;
        const float* nn1gk = nn1_g + (size_t)k * 128;
        const float* nn1bk = nn1_b + (size_t)k * 128;
        const float* nW1k = nW1 + (size_t)k * 160 * 256;
        const float* nb1k = nb1 + (size_t)k * 256;
        const float* nW2k = nW2 + (size_t)k * 256 * 128;
        const float* nb2k = nb2 + (size_t)k * 128;
        const float* nn2gk = nn2_g + (size_t)k * 128;
        const float* nn2bk = nn2_b + (size_t)k * 128;

        k_w1ab<<<768, 256, 0, stream>>>(eW1k, W1ab);
        k_gemm<<<dim3(79, 12), 256, 0, stream>>>(feats_all + k * 128, 768, W1ab, 1536,
                                                 nullptr, Pab, 1536, N_NODES, 1536, 128, 0, 0);
        hipMemsetAsync(S, 0, (size_t)330000 * sizeof(float), stream);
        k_edge<<<N_EDGES / EPB, 256, 0, stream>>>(feT, Pab, eidx,
                                                  W1cp5 + (size_t)k * 65 * 768,
                                                  b1p5 + (size_t)k * 768,
                                                  W2p5 + (size_t)k * 768 * 32,
                                                  eb2k, engk, enbk, S, cnt);
        k_prep<<<N_NODES, 128, 0, stream>>>(feats_all + k * 128, S, cnt,
                                            nn1gk, nn1bk, engk, enbk, H0);
        k_gemm<<<dim3(79, 2), 256, 0, stream>>>(H0, 160, nW1k, 256, nb1k, H1, 256,
                                                N_NODES, 256, 160, 0, 1);
        k_gemm<<<dim3(79, 1), 256, 0, stream>>>(H1, 256, nW2k, 128, nb2k, H2, 128,
                                                N_NODES, 128, 256, 0, 0);
        k_ln_res<<<N_NODES, 128, 0, stream>>>(H2, feats_all, k, nn2gk, nn2bk);
    }

    // final node MLP (F1/F2/F3 overlay Pab)
    k_gemm<<<dim3(79, 2), 256, 0, stream>>>(feats_all, 768, f1W, 256, f1b, F1, 256,
                                            N_NODES, 256, 768, 1, 1);
    k_gemm<<<dim3(79, 2), 256, 0, stream>>>(F1, 256, f2W, 256, f2b, F2, 256,
                                            N_NODES, 256, 256, 0, 1);
    k_gemm<<<dim3(79, 2), 256, 0, stream>>>(F2, 256, f3W, 256, f3b, F3, 256,
                                            N_NODES, 256, 256, 0, 1);

    hipMemsetAsync(G, 0, (size_t)(16384 + 64) * sizeof(float), stream);
    k_pool<<<313, 256, 0, stream>>>(F3, batch, G, cntg);
    k_graph<<<N_GRAPHS, 256, 0, stream>>>(G, cntg, g1W, g1b, g2W, g2b, g3W, g3b, out);
}

// Round 7
// 4857.085 us; speedup vs baseline: 1.7425x; 1.7425x over previous
//
#include <hip/hip_runtime.h>
#include <hip/hip_bf16.h>

#define N_NODES 10000
#define N_EDGES 160000
#define N_GRAPHS 64
#define NK 5
#define EPS 1e-5f
#define EPB 128          // edges per block
#define JP 768           // padded edge-MLP width (642 -> 768), pads are true zeros
#define CHC 128          // cols per chunk
#define NCH 6            // JP / CHC
#define PSTRIDE 1536     // Pab row stride: [Pa 768 | Pb 768]

__device__ __forceinline__ float silu(float x) { return x / (1.0f + __expf(-x)); }
__device__ __forceinline__ float4 f4fma(float s, float4 w, float4 a) {
    a.x = fmaf(s, w.x, a.x); a.y = fmaf(s, w.y, a.y);
    a.z = fmaf(s, w.z, a.z); a.w = fmaf(s, w.w, a.w);
    return a;
}
__device__ __forceinline__ float wave_sum64(float v) {
    #pragma unroll
    for (int off = 32; off > 0; off >>= 1) v += __shfl_xor(v, off, 64);
    return v;
}

// ---------------- embedding ----------------
__global__ __launch_bounds__(128) void k_embed(const int* __restrict__ atomids,
                                               const float* __restrict__ emb_w,
                                               float* __restrict__ feats_all) {
    int n = blockIdx.x, tid = threadIdx.x;
    feats_all[(size_t)n * 768 + tid] = emb_w[(size_t)atomids[n] * 128 + tid];
}

// ---------------- fourier table, transposed: feT[k][e] ----------------
__global__ __launch_bounds__(64) void k_fe(const float* __restrict__ coords,
                                           const int* __restrict__ eidx,
                                           float* __restrict__ feT) {
    int e = blockIdx.x * 64 + threadIdx.x;
    if (e >= N_EDGES) return;
    int s = eidx[e], d = eidx[N_EDGES + e];
    float dx = coords[s * 3 + 0] - coords[d * 3 + 0];
    float dy = coords[s * 3 + 1] - coords[d * 3 + 1];
    float dz = coords[s * 3 + 2] - coords[d * 3 + 2];
    float d2 = dx * dx + dy * dy + dz * dz;
    float sc = 1.0f;
    #pragma unroll
    for (int i = 0; i < 32; ++i) {
        float x = d2 * sc;
        feT[(size_t)i * N_EDGES + e] = sinf(x);
        feT[(size_t)(32 + i) * N_EDGES + e] = cosf(x);
        sc *= 0.5f;
    }
    feT[(size_t)64 * N_EDGES + e] = d2;
}

// ---------------- W1ab prestage, all 5 layers: [5][128][1536] = [W1a | 0 | W1b | 0] ----------------
__global__ __launch_bounds__(256) void k_w1ab5(const float* __restrict__ eW1,  // [5][321][642]
                                               float* __restrict__ W1ab5) {
    int k = blockIdx.y;
    const float* W1 = eW1 + (size_t)k * 321 * 642;
    float* W1ab = W1ab5 + (size_t)k * 128 * 1536;
    int idx = blockIdx.x * 256 + threadIdx.x;
    if (idx >= 128 * 1536) return;
    int r = idx / 1536;
    int j = idx - r * 1536;
    float v = 0.f;
    if (j < 642) v = W1[(size_t)r * 642 + j];
    else if (j >= 768 && j < 1410) v = W1[(size_t)(128 + r) * 642 + (j - 768)];
    W1ab[idx] = v;
}

// ---------------- batched padded edge-weight prestage (all 5 layers) ----------------
__global__ __launch_bounds__(256) void k_wpre5(const float* __restrict__ eW1,  // [5][321][642]
                                               const float* __restrict__ eb1,  // [5][642]
                                               const float* __restrict__ eW2,  // [5][642][32]
                                               float* __restrict__ W1cp5,      // [5][65][768]
                                               float* __restrict__ b1p5,       // [5][768]
                                               float* __restrict__ W2p5) {     // [5][768][32]
    int k = blockIdx.y;
    const float* W1 = eW1 + (size_t)k * 321 * 642;
    const float* b1 = eb1 + (size_t)k * 642;
    const float* W2 = eW2 + (size_t)k * 642 * 32;
    float* W1cp = W1cp5 + (size_t)k * 65 * 768;
    float* b1p  = b1p5 + (size_t)k * 768;
    float* W2p  = W2p5 + (size_t)k * 768 * 32;
    int idx = blockIdx.x * 256 + threadIdx.x;
    if (idx < 65 * 768) {
        int r = idx / 768, j = idx - r * 768;
        W1cp[idx] = (j < 642) ? W1[(size_t)(256 + r) * 642 + j] : 0.f;
    } else if (idx < 65 * 768 + 768) {
        int j = idx - 65 * 768;
        b1p[j] = (j < 642) ? b1[j] : 0.f;
    } else if (idx < 65 * 768 + 768 + 768 * 32) {
        int t = idx - (65 * 768 + 768);
        int j = t >> 5, c = t & 31;
        W2p[t] = (j < 642) ? W2[(size_t)j * 32 + c] : 0.f;
    }
}

// ---------------- fp32 GEMM: C = act(actA(A)[M][K] @ B[K][N] + bias) ----------------
__global__ __launch_bounds__(256) void k_gemm(const float* __restrict__ A, int lda,
                                              const float* __restrict__ B, int ldb,
                                              const float* __restrict__ bias,
                                              float* __restrict__ C, int ldc,
                                              int M, int N, int K, int siluA, int siluOut) {
    __shared__ float As[32 * 132];
    __shared__ float Bs[32 * 132];
    const int tid = threadIdx.x;
    const int m0 = blockIdx.x * 128, n0 = blockIdx.y * 128;
    const int tm = tid >> 4, tn = tid & 15;

    float4 acc[8][2];
    #pragma unroll
    for (int r = 0; r < 8; ++r) { acc[r][0] = make_float4(0,0,0,0); acc[r][1] = make_float4(0,0,0,0); }

    for (int kc = 0; kc < K; kc += 32) {
        #pragma unroll
        for (int i = 0; i < 4; ++i) {
            int idx = tid + i * 256;
            int m = idx >> 3, kq = idx & 7;
            int gm = m0 + m;
            int cm = (gm < M) ? gm : (M - 1);
            float4 a = *(const float4*)(A + (size_t)cm * lda + kc + 4 * kq);
            if (gm >= M) a = make_float4(0,0,0,0);
            if (siluA) { a.x = silu(a.x); a.y = silu(a.y); a.z = silu(a.z); a.w = silu(a.w); }
            As[(4 * kq + 0) * 132 + m] = a.x;
            As[(4 * kq + 1) * 132 + m] = a.y;
            As[(4 * kq + 2) * 132 + m] = a.z;
            As[(4 * kq + 3) * 132 + m] = a.w;
        }
        #pragma unroll
        for (int i = 0; i < 4; ++i) {
            int idx = tid + i * 256;
            int r = idx >> 5, cq = idx & 31;
            int gn = n0 + 4 * cq;
            float4 b = make_float4(0,0,0,0);
            if (gn < N) b = *(const float4*)(B + (size_t)(kc + r) * ldb + gn);
            *(float4*)&Bs[r * 132 + 4 * cq] = b;
        }
        __syncthreads();
        #pragma unroll 4
        for (int kk = 0; kk < 32; ++kk) {
            float4 a0 = *(const float4*)&As[kk * 132 + 8 * tm];
            float4 a1 = *(const float4*)&As[kk * 132 + 8 * tm + 4];
            float4 b0 = *(const float4*)&Bs[kk * 132 + 4 * tn];
            float4 b1 = *(const float4*)&Bs[kk * 132 + 64 + 4 * tn];
            acc[0][0] = f4fma(a0.x, b0, acc[0][0]); acc[0][1] = f4fma(a0.x, b1, acc[0][1]);
            acc[1][0] = f4fma(a0.y, b0, acc[1][0]); acc[1][1] = f4fma(a0.y, b1, acc[1][1]);
            acc[2][0] = f4fma(a0.z, b0, acc[2][0]); acc[2][1] = f4fma(a0.z, b1, acc[2][1]);
            acc[3][0] = f4fma(a0.w, b0, acc[3][0]); acc[3][1] = f4fma(a0.w, b1, acc[3][1]);
            acc[4][0] = f4fma(a1.x, b0, acc[4][0]); acc[4][1] = f4fma(a1.x, b1, acc[4][1]);
            acc[5][0] = f4fma(a1.y, b0, acc[5][0]); acc[5][1] = f4fma(a1.y, b1, acc[5][1]);
            acc[6][0] = f4fma(a1.z, b0, acc[6][0]); acc[6][1] = f4fma(a1.z, b1, acc[6][1]);
            acc[7][0] = f4fma(a1.w, b0, acc[7][0]); acc[7][1] = f4fma(a1.w, b1, acc[7][1]);
        }
        __syncthreads();
    }

    const int gnl = n0 + 4 * tn, gnh = n0 + 64 + 4 * tn;
    #pragma unroll
    for (int r = 0; r < 8; ++r) {
        int gm = m0 + 8 * tm + r;
        if (gm >= M) continue;
        float4 v0 = acc[r][0], v1 = acc[r][1];
        if (gnl < N) {
            if (bias) { v0.x += bias[gnl+0]; v0.y += bias[gnl+1]; v0.z += bias[gnl+2]; v0.w += bias[gnl+3]; }
            if (siluOut) { v0.x = silu(v0.x); v0.y = silu(v0.y); v0.z = silu(v0.z); v0.w = silu(v0.w); }
            *(float4*)&C[(size_t)gm * ldc + gnl] = v0;
        }
        if (gnh < N) {
            if (bias) { v1.x += bias[gnh+0]; v1.y += bias[gnh+1]; v1.z += bias[gnh+2]; v1.w += bias[gnh+3]; }
            if (siluOut) { v1.x = silu(v1.x); v1.y = silu(v1.y); v1.z = silu(v1.z); v1.w = silu(v1.w); }
            *(float4*)&C[(size_t)gm * ldc + gnh] = v1;
        }
    }
}

// ---------------- fused edge kernel: round-5 dataflow, 3 blocks/CU, wave-aligned phase-1 ----------------
// LDS ~47 KB: feTs half-staged [33][132], W1s half-staged [33][132], Zs [16][132] (8 passes),
// W2s [16][36]. Phase1: qa = Pa[dst]+Pb[src]+b1 then += fe@W1 (qa[8][8] regs only).
// Phase2: round-5 scheme (accm = 4 x float4), 16-j passes. Epilogue: +b2, silu, LN, scatter.
__global__ __launch_bounds__(256, 3) void k_edge(const float* __restrict__ feT,   // [65][N_EDGES]
                                                 const float* __restrict__ Pab,   // [N_NODES][1536]
                                                 const int* __restrict__ eidx,
                                                 const float* __restrict__ W1cp,  // [65][768]
                                                 const float* __restrict__ b1p,   // [768]
                                                 const float* __restrict__ W2p,   // [768][32]
                                                 const float* __restrict__ b2,
                                                 const float* __restrict__ eng,
                                                 const float* __restrict__ enb,
                                                 float* __restrict__ S,
                                                 float* __restrict__ cnt) {
    __shared__ float U[11400];         // feTs 4356 | W1s 4356 | Zs 2112 | W2s 576
    __shared__ int dsi[EPB], ssi[EPB];
    __shared__ float cpar[96];
    float* feTs = U;                   // [33][132]
    float* W1s  = U + 4356;            // [33][132]
    float* Zs   = U + 8712;            // [16][132]
    float* W2s  = U + 10824;           // [16][36]
    float* m2s  = U;                   // [128][36] epilogue overlay (feTs+W1s region)

    const int tid = threadIdx.x;
    const int w = tid >> 6, lane = tid & 63;
    const int eb = blockIdx.x * EPB;
    // phase-1: wave-aligned 8x8 -> 2-way LDS max
    const int et = (lane & 7) | ((w & 1) << 3);          // edges 8*et..
    const int cg = ((lane >> 3) & 7) | ((w >> 1) << 3);  // cols 8*cg..
    // phase-2 (round-5): 4 edges x 4 cols
    const int eg = tid >> 3, cq = tid & 7;

    if (tid < EPB) {
        ssi[tid] = eidx[eb + tid];
        dsi[tid] = eidx[N_EDGES + eb + tid];
    }
    if (tid < 32) cpar[tid] = b2[tid];
    else if (tid < 64) cpar[tid] = eng[tid - 32];
    else if (tid < 96) cpar[tid] = enb[tid - 64];
    __syncthreads();

    int dsr[8], ssr[8];
    #pragma unroll
    for (int i = 0; i < 8; ++i) { dsr[i] = dsi[8 * et + i]; ssr[i] = ssi[8 * et + i]; }

    float4 accm[4];
    #pragma unroll
    for (int i = 0; i < 4; ++i) accm[i] = make_float4(0,0,0,0);

    for (int ch = 0; ch < NCH; ++ch) {
        const int jc = ch * CHC;

        // ---- qa init: gathered Pa/Pb + b1 (loads issue early; adds consume) ----
        float qa[8][8];
        {
            float4 blo = *(const float4*)(b1p + jc + 8 * cg);
            float4 bhi = *(const float4*)(b1p + jc + 8 * cg + 4);
            #pragma unroll
            for (int i = 0; i < 8; ++i) {
                const float* pr = Pab + (size_t)dsr[i] * PSTRIDE + jc + 8 * cg;
                const float* qr = Pab + (size_t)ssr[i] * PSTRIDE + JP + jc + 8 * cg;
                float4 a0 = *(const float4*)pr;
                float4 a1 = *(const float4*)(pr + 4);
                float4 c0 = *(const float4*)qr;
                float4 c1 = *(const float4*)(qr + 4);
                qa[i][0] = a0.x + c0.x + blo.x; qa[i][1] = a0.y + c0.y + blo.y;
                qa[i][2] = a0.z + c0.z + blo.z; qa[i][3] = a0.w + c0.w + blo.w;
                qa[i][4] = a1.x + c1.x + bhi.x; qa[i][5] = a1.y + c1.y + bhi.y;
                qa[i][6] = a1.z + c1.z + bhi.z; qa[i][7] = a1.w + c1.w + bhi.w;
            }
        }

        // ---- half A: stage fe rows 0..32 + W1 rows 0..32, compute ----
        __syncthreads();   // feTs/W1s free (prev chunk compute done), Zs handled by pass syncs
        #pragma unroll
        for (int i = 0; i < 5; ++i) {
            int idx = tid + i * 256;
            if (idx < 33 * 32) {
                int r = idx >> 5, q = idx & 31;
                *(float4*)&feTs[r * 132 + 4 * q] = *(const float4*)(feT + (size_t)r * N_EDGES + eb + 4 * q);
                *(float4*)&W1s[r * 132 + 4 * q]  = *(const float4*)(W1cp + (size_t)r * 768 + jc + 4 * q);
            }
        }
        __syncthreads();
        for (int kk = 0; kk < 33; ++kk) {
            float4 f0 = *(const float4*)&feTs[kk * 132 + 8 * et];
            float4 f1 = *(const float4*)&feTs[kk * 132 + 8 * et + 4];
            float4 w0 = *(const float4*)&W1s[kk * 132 + 8 * cg];
            float4 w1 = *(const float4*)&W1s[kk * 132 + 8 * cg + 4];
            float fv[8] = {f0.x, f0.y, f0.z, f0.w, f1.x, f1.y, f1.z, f1.w};
            float wv[8] = {w0.x, w0.y, w0.z, w0.w, w1.x, w1.y, w1.z, w1.w};
            #pragma unroll
            for (int i = 0; i < 8; ++i)
                #pragma unroll
                for (int c = 0; c < 8; ++c) qa[i][c] = fmaf(fv[i], wv[c], qa[i][c]);
        }
        __syncthreads();
        // ---- half B: stage fe rows 33..64 + W1 rows 33..64, compute ----
        #pragma unroll
        for (int i = 0; i < 4; ++i) {
            int idx = tid + i * 256;
            if (idx < 32 * 32) {
                int r = idx >> 5, q = idx & 31;
                *(float4*)&feTs[r * 132 + 4 * q] = *(const float4*)(feT + (size_t)(33 + r) * N_EDGES + eb + 4 * q);
                *(float4*)&W1s[r * 132 + 4 * q]  = *(const float4*)(W1cp + (size_t)(33 + r) * 768 + jc + 4 * q);
            }
        }
        __syncthreads();
        for (int kk = 0; kk < 32; ++kk) {
            float4 f0 = *(const float4*)&feTs[kk * 132 + 8 * et];
            float4 f1 = *(const float4*)&feTs[kk * 132 + 8 * et + 4];
            float4 w0 = *(const float4*)&W1s[kk * 132 + 8 * cg];
            float4 w1 = *(const float4*)&W1s[kk * 132 + 8 * cg + 4];
            float fv[8] = {f0.x, f0.y, f0.z, f0.w, f1.x, f1.y, f1.z, f1.w};
            float wv[8] = {w0.x, w0.y, w0.z, w0.w, w1.x, w1.y, w1.z, w1.w};
            #pragma unroll
            for (int i = 0; i < 8; ++i)
                #pragma unroll
                for (int c = 0; c < 8; ++c) qa[i][c] = fmaf(fv[i], wv[c], qa[i][c]);
        }

        // ---- z = silu(qa) ----
        #pragma unroll
        for (int i = 0; i < 8; ++i)
            #pragma unroll
            for (int c = 0; c < 8; ++c) qa[i][c] = silu(qa[i][c]);

        // ---- phase 2: 8 passes of 16 j ----
        #pragma unroll
        for (int p = 0; p < 8; ++p) {
            __syncthreads();   // previous pass reads done
            if ((cg >> 1) == p) {
                int jl = 8 * (cg & 1);       // 0 or 8
                #pragma unroll
                for (int jj = 0; jj < 8; ++jj) {
                    *(float4*)&Zs[(jl + jj) * 132 + 8 * et]     = make_float4(qa[0][jj], qa[1][jj], qa[2][jj], qa[3][jj]);
                    *(float4*)&Zs[(jl + jj) * 132 + 8 * et + 4] = make_float4(qa[4][jj], qa[5][jj], qa[6][jj], qa[7][jj]);
                }
            }
            if (tid < 128) {   // stage W2s rows for this pass
                int r = tid >> 3, q = tid & 7;
                *(float4*)&W2s[r * 36 + 4 * q] = *(const float4*)(W2p + (size_t)(jc + 16 * p + r) * 32 + 4 * q);
            }
            __syncthreads();
            #pragma unroll 4
            for (int kk = 0; kk < 16; ++kk) {
                float4 z4 = *(const float4*)&Zs[kk * 132 + 4 * eg];
                float4 w4 = *(const float4*)&W2s[kk * 36 + 4 * cq];
                accm[0] = f4fma(z4.x, w4, accm[0]);
                accm[1] = f4fma(z4.y, w4, accm[1]);
                accm[2] = f4fma(z4.z, w4, accm[2]);
                accm[3] = f4fma(z4.w, w4, accm[3]);
            }
        }
    }

    // ---- epilogue: m2 = silu(accm + b2), LN, scatter ----
    __syncthreads();
    {
        float4 bb2 = *(const float4*)&cpar[4 * cq];
        #pragma unroll
        for (int i = 0; i < 4; ++i) {
            int e = 4 * eg + i;
            m2s[e * 36 + 4 * cq + 0] = silu(accm[i].x + bb2.x);
            m2s[e * 36 + 4 * cq + 1] = silu(accm[i].y + bb2.y);
            m2s[e * 36 + 4 * cq + 2] = silu(accm[i].z + bb2.z);
            m2s[e * 36 + 4 * cq + 3] = silu(accm[i].w + bb2.w);
        }
    }
    __syncthreads();
    if (tid < EPB) {
        float s = 0.f, ss = 0.f;
        float v[32];
        #pragma unroll
        for (int c = 0; c < 32; ++c) {
            float x = m2s[tid * 36 + c];
            v[c] = x; s += x; ss += x * x;
        }
        float mean = s * 0.03125f;
        float var = ss * 0.03125f - mean * mean;
        float rstd = 1.0f / sqrtf(var + EPS);
        int d = dsi[tid];
        float* Sp = S + (size_t)d * 32;
        #pragma unroll
        for (int c = 0; c < 32; ++c) {
            float y = (v[c] - mean) * rstd * cpar[32 + c] + cpar[64 + c];
            atomicAdd(&Sp[c], y);
        }
        atomicAdd(&cnt[d], 1.0f);
    }
}

// ---------------- node prep: H0 = [LN(feats) | LN(S/cnt)] ----------------
__global__ __launch_bounds__(128) void k_prep(const float* __restrict__ featsk,
                                              const float* __restrict__ S,
                                              const float* __restrict__ cnt,
                                              const float* __restrict__ nn1g,
                                              const float* __restrict__ nn1b,
                                              const float* __restrict__ eng,
                                              const float* __restrict__ enb,
                                              float* __restrict__ H0) {
    int n = blockIdx.x, tid = threadIdx.x;
    __shared__ float red[4];
    float x = featsk[(size_t)n * 768 + tid];
    float s = wave_sum64(x), ss = wave_sum64(x * x);
    if ((tid & 63) == 0) { red[(tid >> 6) * 2] = s; red[(tid >> 6) * 2 + 1] = ss; }
    __syncthreads();
    float S1 = red[0] + red[2], S2 = red[1] + red[3];
    float mean = S1 * (1.0f / 128.0f);
    float var = S2 * (1.0f / 128.0f) - mean * mean;
    float rstd = 1.0f / sqrtf(var + EPS);
    H0[(size_t)n * 160 + tid] = (x - mean) * rstd * nn1g[tid] + nn1b[tid];
    if (tid < 32) {
        float inv = 1.0f / fmaxf(cnt[n], 1.0f);
        float v = S[(size_t)n * 32 + tid] * inv;
        float s2 = v, q2 = v * v;
        #pragma unroll
        for (int off = 16; off > 0; off >>= 1) {
            s2 += __shfl_xor(s2, off, 64);
            q2 += __shfl_xor(q2, off, 64);
        }
        float m2 = s2 * (1.0f / 32.0f);
        float va = q2 * (1.0f / 32.0f) - m2 * m2;
        float rs = 1.0f / sqrtf(va + EPS);
        H0[(size_t)n * 160 + 128 + tid] = (v - m2) * rs * eng[tid] + enb[tid];
    }
}

// ---------------- LN + residual ----------------
__global__ __launch_bounds__(128) void k_ln_res(const float* __restrict__ H2,
                                                float* __restrict__ feats_all, int k,
                                                const float* __restrict__ g,
                                                const float* __restrict__ b) {
    int n = blockIdx.x, tid = threadIdx.x;
    __shared__ float red[4];
    float x = H2[(size_t)n * 128 + tid];
    float s = wave_sum64(x), ss = wave_sum64(x * x);
    if ((tid & 63) == 0) { red[(tid >> 6) * 2] = s; red[(tid >> 6) * 2 + 1] = ss; }
    __syncthreads();
    float S1 = red[0] + red[2], S2 = red[1] + red[3];
    float mean = S1 * (1.0f / 128.0f);
    float var = S2 * (1.0f / 128.0f) - mean * mean;
    float rstd = 1.0f / sqrtf(var + EPS);
    float v = (x - mean) * rstd * g[tid] + b[tid];
    float f = feats_all[(size_t)n * 768 + k * 128 + tid];
    feats_all[(size_t)n * 768 + (k + 1) * 128 + tid] = f + v;
}

// ---------------- graph pooling (batch sorted -> run-length accum) ----------------
__global__ __launch_bounds__(256) void k_pool(const float* __restrict__ F,
                                              const int* __restrict__ batch,
                                              float* __restrict__ G,
                                              float* __restrict__ cntg) {
    __shared__ int bL[32];
    int b0 = blockIdx.x * 32;
    int tid = threadIdx.x;
    int nmax = min(32, N_NODES - b0);
    if (nmax <= 0) return;
    if (tid < nmax) bL[tid] = batch[b0 + tid];
    __syncthreads();
    float accv = 0.f;
    int cur = -1;
    for (int i = 0; i < nmax; ++i) {
        int g = bL[i];
        if (g != cur) {
            if (cur >= 0) atomicAdd(&G[(size_t)cur * 256 + tid], accv);
            cur = g; accv = 0.f;
        }
        accv += F[(size_t)(b0 + i) * 256 + tid];
    }
    if (cur >= 0) atomicAdd(&G[(size_t)cur * 256 + tid], accv);
    if (tid == 0)
        for (int i = 0; i < nmax; ++i) atomicAdd(&cntg[bL[i]], 1.0f);
}

// ---------------- per-graph MLP head ----------------
__global__ __launch_bounds__(256) void k_graph(const float* __restrict__ G,
                                               const float* __restrict__ cntg,
                                               const float* __restrict__ g1W,
                                               const float* __restrict__ g1b,
                                               const float* __restrict__ g2W,
                                               const float* __restrict__ g2b,
                                               const float* __restrict__ g3W,
                                               const float* __restrict__ g3b,
                                               float* __restrict__ out) {
    __shared__ float X[256], Y[256], red[4];
    int g = blockIdx.x, tid = threadIdx.x;
    float inv = 1.0f / fmaxf(cntg[g], 1.0f);
    X[tid] = G[(size_t)g * 256 + tid] * inv;
    __syncthreads();
    float a = g1b[tid];
    for (int j = 0; j < 256; ++j) a = fmaf(X[j], g1W[(size_t)j * 256 + tid], a);
    Y[tid] = silu(a);
    __syncthreads();
    a = g2b[tid];
    for (int j = 0; j < 256; ++j) a = fmaf(Y[j], g2W[(size_t)j * 256 + tid], a);
    float z = silu(a);
    float p = z * g3W[tid];
    p = wave_sum64(p);
    if ((tid & 63) == 0) red[tid >> 6] = p;
    __syncthreads();
    if (tid == 0) out[g] = red[0] + red[1] + red[2] + red[3] + g3b[0];
}

extern "C" void kernel_launch(void* const* d_in, const int* in_sizes, int n_in,
                              void* d_out, int out_size, void* d_ws, size_t ws_size,
                              hipStream_t stream) {
    const int*   atomids = (const int*)d_in[0];
    const float* coords  = (const float*)d_in[1];
    const int*   eidx    = (const int*)d_in[2];
    const int*   batch   = (const int*)d_in[3];
    const float* emb_w   = (const float*)d_in[4];
    const float* eW1     = (const float*)d_in[5];
    const float* eb1     = (const float*)d_in[6];
    const float* eW2     = (const float*)d_in[7];
    const float* eb2     = (const float*)d_in[8];
    const float* en_g    = (const float*)d_in[9];
    const float* en_b    = (const float*)d_in[10];
    const float* nn1_g   = (const float*)d_in[11];
    const float* nn1_b   = (const float*)d_in[12];
    const float* nW1     = (const float*)d_in[13];
    const float* nb1     = (const float*)d_in[14];
    const float* nW2     = (const float*)d_in[15];
    const float* nb2     = (const float*)d_in[16];
    const float* nn2_g   = (const float*)d_in[17];
    const float* nn2_b   = (const float*)d_in[18];
    const float* f1W     = (const float*)d_in[19];
    const float* f1b     = (const float*)d_in[20];
    const float* f2W     = (const float*)d_in[21];
    const float* f2b     = (const float*)d_in[22];
    const float* f3W     = (const float*)d_in[23];
    const float* f3b     = (const float*)d_in[24];
    const float* g1W     = (const float*)d_in[25];
    const float* g1b     = (const float*)d_in[26];
    const float* g2W     = (const float*)d_in[27];
    const float* g2b     = (const float*)d_in[28];
    const float* g3W     = (const float*)d_in[29];
    const float* g3b     = (const float*)d_in[30];
    float* out = (float*)d_out;

    float* ws = (float*)d_ws;
    // layout (float indices, 16B-aligned); total ~35.15M floats ~= 140.6 MB
    float* feats_all = ws;                        // [10000][768]
    float* feT   = ws + 7680000;                  // [65][160000]
    float* Pab   = ws + 18080000;                 // [10000][1536]
    float* S     = ws + 33440000;                 // [10000][32]
    float* cnt   = ws + 33760000;                 // [10000]
    float* W1ab5 = ws + 33770000;                 // [5][128][1536]
    float* W1cp5 = ws + 34753040;                 // [5][65][768]
    float* b1p5  = ws + 35002640;                 // [5][768]
    float* W2p5  = ws + 35006480;                 // [5][768][32]
    float* G     = ws + 35129360;                 // [64][256]
    float* cntg  = ws + 35145744;                 // [64]
    // node-phase temporaries overlay Pab (dead between phases)
    float* H0 = Pab;                              // [10000][160]
    float* H1 = Pab + 1600000;                    // [10000][256]
    float* H2 = Pab + 4160000;                    // [10000][128]
    float* F1 = Pab;                              // [10000][256]
    float* F2 = Pab + 2560000;                    // [10000][256]
    float* F3 = Pab + 5120000;                    // [10000][256]

    k_embed<<<N_NODES, 128, 0, stream>>>(atomids, emb_w, feats_all);
    k_fe<<<N_EDGES / 64, 64, 0, stream>>>(coords, eidx, feT);
    k_w1ab5<<<dim3(768, 5), 256, 0, stream>>>(eW1, W1ab5);
    k_wpre5<<<dim3(294, 5), 256, 0, stream>>>(eW1, eb1, eW2, W1cp5, b1p5, W2p5);

    for (int k = 0; k < NK; ++k) {
        const float* eb2k = eb2 + (size_t)k * 32;
        const float* engk = en_g + (size_t)k * 32;
        const float* enbk = en_b + (size_t)k * 32;
        const float* nn1gk = nn1_g + (size_t)k * 128;
        const float* nn1bk = nn1_b + (size_t)k * 128;
        const float* nW1k = nW1 + (size_t)k * 160 * 256;
        const float* nb1k = nb1 + (size_t)k * 256;
        const float* nW2k = nW2 + (size_t)k * 256 * 128;
        const float* nb2k = nb2 + (size_t)k * 128;
        const float* nn2gk = nn2_g + (size_t)k * 128;
        const float* nn2bk = nn2_b + (size_t)k * 128;

        k_gemm<<<dim3(79, 12), 256, 0, stream>>>(feats_all + k * 128, 768,
                                                 W1ab5 + (size_t)k * 128 * 1536, 1536,
                                                 nullptr, Pab, 1536, N_NODES, 1536, 128, 0, 0);
        hipMemsetAsync(S, 0, (size_t)330000 * sizeof(float), stream);
        k_edge<<<N_EDGES / EPB, 256, 0, stream>>>(feT, Pab, eidx,
                                                  W1cp5 + (size_t)k * 65 * 768,
                                                  b1p5 + (size_t)k * 768,
                                                  W2p5 + (size_t)k * 768 * 32,
                                                  eb2k, engk, enbk, S, cnt);
        k_prep<<<N_NODES, 128, 0, stream>>>(feats_all + k * 128, S, cnt,
                                            nn1gk, nn1bk, engk, enbk, H0);
        k_gemm<<<dim3(79, 2), 256, 0, stream>>>(H0, 160, nW1k, 256, nb1k, H1, 256,
                                                N_NODES, 256, 160, 0, 1);
        k_gemm<<<dim3(79, 1), 256, 0, stream>>>(H1, 256, nW2k, 128, nb2k, H2, 128,
                                                N_NODES, 128, 256, 0, 0);
        k_ln_res<<<N_NODES, 128, 0, stream>>>(H2, feats_all, k, nn2gk, nn2bk);
    }

    // final node MLP (F1/F2/F3 overlay Pab)
    k_gemm<<<dim3(79, 2), 256, 0, stream>>>(feats_all, 768, f1W, 256, f1b, F1, 256,
                                            N_NODES, 256, 768, 1, 1);
    k_gemm<<<dim3(79, 2), 256, 0, stream>>>(F1, 256, f2W, 256, f2b, F2, 256,
                                            N_NODES, 256, 256, 0, 1);
    k_gemm<<<dim3(79, 2), 256, 0, stream>>>(F2, 256, f3W, 256, f3b, F3, 256,
                                            N_NODES, 256, 256, 0, 1);

    hipMemsetAsync(G, 0, (size_t)(16384 + 64) * sizeof(float), stream);
    k_pool<<<313, 256, 0, stream>>>(F3, batch, G, cntg);
    k_graph<<<N_GRAPHS, 256, 0, stream>>>(G, cntg, g1W, g1b, g2W, g2b, g3W, g3b, out);
}

// Round 8
// 4024.394 us; speedup vs baseline: 2.1030x; 1.2069x over previous
//
#include <hip/hip_runtime.h>
#include <hip/hip_bf16.h>

#define N_NODES 10000
#define N_EDGES 160000
#define N_GRAPHS 64
#define NK 5
#define EPS 1e-5f
#define EPB 128          // edges per block
#define JP 768           // padded width for Pab halves
#define PSTRIDE 1536     // Pab row stride: [Pa 768 | Pb 768]
#define TCOLS 648        // table row width (642 -> 648)
#define TROWS 12289      // d2 grid [0,96], h=1/128
#define IMAX 12287

__device__ __forceinline__ float silu(float x) { return x / (1.0f + __expf(-x)); }
__device__ __forceinline__ float4 f4fma(float s, float4 w, float4 a) {
    a.x = fmaf(s, w.x, a.x); a.y = fmaf(s, w.y, a.y);
    a.z = fmaf(s, w.z, a.z); a.w = fmaf(s, w.w, a.w);
    return a;
}
__device__ __forceinline__ float wave_sum64(float v) {
    #pragma unroll
    for (int off = 32; off > 0; off >>= 1) v += __shfl_xor(v, off, 64);
    return v;
}

// ---------------- embedding ----------------
__global__ __launch_bounds__(128) void k_embed(const int* __restrict__ atomids,
                                               const float* __restrict__ emb_w,
                                               float* __restrict__ feats_all) {
    int n = blockIdx.x, tid = threadIdx.x;
    feats_all[(size_t)n * 768 + tid] = emb_w[(size_t)atomids[n] * 128 + tid];
}

// ---------------- per-edge squared distance ----------------
__global__ __launch_bounds__(256) void k_d2(const float* __restrict__ coords,
                                            const int* __restrict__ eidx,
                                            float* __restrict__ d2g) {
    int e = blockIdx.x * 256 + threadIdx.x;
    if (e >= N_EDGES) return;
    int s = eidx[e], d = eidx[N_EDGES + e];
    float dx = coords[s * 3 + 0] - coords[d * 3 + 0];
    float dy = coords[s * 3 + 1] - coords[d * 3 + 1];
    float dz = coords[s * 3 + 2] - coords[d * 3 + 2];
    d2g[e] = dx * dx + dy * dy + dz * dz;
}

// ---------------- fourier features on the d2 GRID (once; layer-independent) ----------------
__global__ __launch_bounds__(256) void k_feg(float* __restrict__ feG) {  // [TROWS][68]
    int g = blockIdx.x * 256 + threadIdx.x;
    if (g >= TROWS) return;
    float d2v = (float)g * 0.0078125f;   // g / 128, exact
    float* o = feG + (size_t)g * 68;
    float sc = 1.0f;
    #pragma unroll
    for (int i = 0; i < 32; ++i) {
        float x = d2v * sc;
        o[i] = sinf(x);
        o[32 + i] = cosf(x);
        sc *= 0.5f;
    }
    o[64] = d2v;
}

// ---------------- per-layer q-table: T[g][j] = fe(g/128) @ W1c + b1 ----------------
// 32 g per block; col chunks of 32.
__global__ __launch_bounds__(256) void k_tab(const float* __restrict__ feG,   // [TROWS][68]
                                             const float* __restrict__ W1cp,  // [65][768] padded
                                             const float* __restrict__ b1p,   // [768] padded
                                             float* __restrict__ T) {         // [TROWS][648]
    __shared__ float feGs[32 * 68];
    __shared__ float W1s[65 * 36];
    const int tid = threadIdx.x;
    const int g0 = blockIdx.x * 32;
    for (int idx = tid; idx < 32 * 17; idx += 256) {
        int r = idx / 17, c = idx - r * 17;
        int gi = g0 + r;
        float4 v = make_float4(0, 0, 0, 0);
        if (gi < TROWS) v = *(const float4*)(feG + (size_t)gi * 68 + 4 * c);
        *(float4*)&feGs[r * 68 + 4 * c] = v;
    }
    const int gt = tid >> 3, ct = tid & 7;   // 32 g x 8 col-quads
    for (int jc = 0; jc < TCOLS; jc += 32) {
        __syncthreads();
        for (int idx = tid; idx < 65 * 32; idx += 256) {
            int k = idx >> 5, j = idx & 31;
            W1s[k * 36 + j] = W1cp[(size_t)k * 768 + jc + j];   // cols < 768 always
        }
        __syncthreads();
        int gj = jc + 4 * ct;
        float4 q = *(const float4*)(b1p + gj);
        #pragma unroll 5
        for (int k = 0; k < 65; ++k) {
            float f = feGs[gt * 68 + k];
            float4 w = *(const float4*)&W1s[k * 36 + 4 * ct];
            q = f4fma(f, w, q);
        }
        int g = g0 + gt;
        if (g < TROWS && gj < TCOLS)
            *(float4*)(T + (size_t)g * TCOLS + gj) = q;
    }
}

// ---------------- W1ab prestage, all 5 layers: [5][128][1536] = [W1a | 0 | W1b | 0] ----------------
__global__ __launch_bounds__(256) void k_w1ab5(const float* __restrict__ eW1,
                                               float* __restrict__ W1ab5) {
    int k = blockIdx.y;
    const float* W1 = eW1 + (size_t)k * 321 * 642;
    float* W1ab = W1ab5 + (size_t)k * 128 * 1536;
    int idx = blockIdx.x * 256 + threadIdx.x;
    if (idx >= 128 * 1536) return;
    int r = idx / 1536;
    int j = idx - r * 1536;
    float v = 0.f;
    if (j < 642) v = W1[(size_t)r * 642 + j];
    else if (j >= 768 && j < 1410) v = W1[(size_t)(128 + r) * 642 + (j - 768)];
    W1ab[idx] = v;
}

// ---------------- padded edge-weight prestage (all 5 layers) ----------------
__global__ __launch_bounds__(256) void k_wpre5(const float* __restrict__ eW1,
                                               const float* __restrict__ eb1,
                                               const float* __restrict__ eW2,
                                               float* __restrict__ W1cp5,   // [5][65][768]
                                               float* __restrict__ b1p5,    // [5][768]
                                               float* __restrict__ W2p5) {  // [5][768][32]
    int k = blockIdx.y;
    const float* W1 = eW1 + (size_t)k * 321 * 642;
    const float* b1 = eb1 + (size_t)k * 642;
    const float* W2 = eW2 + (size_t)k * 642 * 32;
    float* W1cp = W1cp5 + (size_t)k * 65 * 768;
    float* b1p  = b1p5 + (size_t)k * 768;
    float* W2p  = W2p5 + (size_t)k * 768 * 32;
    int idx = blockIdx.x * 256 + threadIdx.x;
    if (idx < 65 * 768) {
        int r = idx / 768, j = idx - r * 768;
        W1cp[idx] = (j < 642) ? W1[(size_t)(256 + r) * 642 + j] : 0.f;
    } else if (idx < 65 * 768 + 768) {
        int j = idx - 65 * 768;
        b1p[j] = (j < 642) ? b1[j] : 0.f;
    } else if (idx < 65 * 768 + 768 + 768 * 32) {
        int t = idx - (65 * 768 + 768);
        int j = t >> 5, c = t & 31;
        W2p[t] = (j < 642) ? W2[(size_t)j * 32 + c] : 0.f;
    }
}

// ---------------- fp32 GEMM: C = act(actA(A)[M][K] @ B[K][N] + bias) ----------------
__global__ __launch_bounds__(256) void k_gemm(const float* __restrict__ A, int lda,
                                              const float* __restrict__ B, int ldb,
                                              const float* __restrict__ bias,
                                              float* __restrict__ C, int ldc,
                                              int M, int N, int K, int siluA, int siluOut) {
    __shared__ float As[32 * 132];
    __shared__ float Bs[32 * 132];
    const int tid = threadIdx.x;
    const int m0 = blockIdx.x * 128, n0 = blockIdx.y * 128;
    const int tm = tid >> 4, tn = tid & 15;

    float4 acc[8][2];
    #pragma unroll
    for (int r = 0; r < 8; ++r) { acc[r][0] = make_float4(0,0,0,0); acc[r][1] = make_float4(0,0,0,0); }

    for (int kc = 0; kc < K; kc += 32) {
        #pragma unroll
        for (int i = 0; i < 4; ++i) {
            int idx = tid + i * 256;
            int m = idx >> 3, kq = idx & 7;
            int gm = m0 + m;
            int cm = (gm < M) ? gm : (M - 1);
            float4 a = *(const float4*)(A + (size_t)cm * lda + kc + 4 * kq);
            if (gm >= M) a = make_float4(0,0,0,0);
            if (siluA) { a.x = silu(a.x); a.y = silu(a.y); a.z = silu(a.z); a.w = silu(a.w); }
            As[(4 * kq + 0) * 132 + m] = a.x;
            As[(4 * kq + 1) * 132 + m] = a.y;
            As[(4 * kq + 2) * 132 + m] = a.z;
            As[(4 * kq + 3) * 132 + m] = a.w;
        }
        #pragma unroll
        for (int i = 0; i < 4; ++i) {
            int idx = tid + i * 256;
            int r = idx >> 5, cq = idx & 31;
            int gn = n0 + 4 * cq;
            float4 b = make_float4(0,0,0,0);
            if (gn < N) b = *(const float4*)(B + (size_t)(kc + r) * ldb + gn);
            *(float4*)&Bs[r * 132 + 4 * cq] = b;
        }
        __syncthreads();
        #pragma unroll 4
        for (int kk = 0; kk < 32; ++kk) {
            float4 a0 = *(const float4*)&As[kk * 132 + 8 * tm];
            float4 a1 = *(const float4*)&As[kk * 132 + 8 * tm + 4];
            float4 b0 = *(const float4*)&Bs[kk * 132 + 4 * tn];
            float4 b1 = *(const float4*)&Bs[kk * 132 + 64 + 4 * tn];
            acc[0][0] = f4fma(a0.x, b0, acc[0][0]); acc[0][1] = f4fma(a0.x, b1, acc[0][1]);
            acc[1][0] = f4fma(a0.y, b0, acc[1][0]); acc[1][1] = f4fma(a0.y, b1, acc[1][1]);
            acc[2][0] = f4fma(a0.z, b0, acc[2][0]); acc[2][1] = f4fma(a0.z, b1, acc[2][1]);
            acc[3][0] = f4fma(a0.w, b0, acc[3][0]); acc[3][1] = f4fma(a0.w, b1, acc[3][1]);
            acc[4][0] = f4fma(a1.x, b0, acc[4][0]); acc[4][1] = f4fma(a1.x, b1, acc[4][1]);
            acc[5][0] = f4fma(a1.y, b0, acc[5][0]); acc[5][1] = f4fma(a1.y, b1, acc[5][1]);
            acc[6][0] = f4fma(a1.z, b0, acc[6][0]); acc[6][1] = f4fma(a1.z, b1, acc[6][1]);
            acc[7][0] = f4fma(a1.w, b0, acc[7][0]); acc[7][1] = f4fma(a1.w, b1, acc[7][1]);
        }
        __syncthreads();
    }

    const int gnl = n0 + 4 * tn, gnh = n0 + 64 + 4 * tn;
    #pragma unroll
    for (int r = 0; r < 8; ++r) {
        int gm = m0 + 8 * tm + r;
        if (gm >= M) continue;
        float4 v0 = acc[r][0], v1 = acc[r][1];
        if (gnl < N) {
            if (bias) { v0.x += bias[gnl+0]; v0.y += bias[gnl+1]; v0.z += bias[gnl+2]; v0.w += bias[gnl+3]; }
            if (siluOut) { v0.x = silu(v0.x); v0.y = silu(v0.y); v0.z = silu(v0.z); v0.w = silu(v0.w); }
            *(float4*)&C[(size_t)gm * ldc + gnl] = v0;
        }
        if (gnh < N) {
            if (bias) { v1.x += bias[gnh+0]; v1.y += bias[gnh+1]; v1.z += bias[gnh+2]; v1.w += bias[gnh+3]; }
            if (siluOut) { v1.x = silu(v1.x); v1.y = silu(v1.y); v1.z = silu(v1.z); v1.w = silu(v1.w); }
            *(float4*)&C[(size_t)gm * ldc + gnh] = v1;
        }
    }
}

// ---------------- fused edge kernel: table-lerp phase-1, round-5 phase-2 ----------------
// 128 edges/block, 11 chunks of 64 cols (cols 704..767 are all-zero, skipped).
// Phase1 (et=tid&31: 4 edges, cg=tid>>5: 8 cols): q = lerp(T[i0],T[i0+1]) + Pa[dst] + Pb[src]; z=silu(q).
// Phase2: 2 passes of 32 j via Zs round-trip; accm = 4 x float4. Epilogue: +b2, silu, LN, scatter.
__global__ __launch_bounds__(256) void k_edge(const float* __restrict__ d2g,
                                              const float* __restrict__ T,     // [TROWS][648]
                                              const float* __restrict__ Pab,   // [N_NODES][1536]
                                              const int* __restrict__ eidx,
                                              const float* __restrict__ W2p,   // [768][32]
                                              const float* __restrict__ b2,
                                              const float* __restrict__ eng,
                                              const float* __restrict__ enb,
                                              float* __restrict__ S,
                                              float* __restrict__ cnt) {
    __shared__ float U[5376];            // Zs[32][132] | W2s[32][36]; overlay m2s[128][36]
    __shared__ int dsi[EPB], ssi[EPB], i0s[EPB];
    __shared__ float frs[EPB];
    __shared__ float cpar[96];
    float* Zs  = U;
    float* W2s = U + 4224;
    float* m2s = U;

    const int tid = threadIdx.x;
    const int eb = blockIdx.x * EPB;
    const int et = tid & 31, cg = tid >> 5;   // phase-1: edges 4*et.., cols 8*cg..
    const int eg = tid >> 3, cq = tid & 7;    // phase-2: edges 4*eg.., cols 4*cq..

    if (tid < EPB) {
        ssi[tid] = eidx[eb + tid];
        dsi[tid] = eidx[N_EDGES + eb + tid];
        float t = d2g[eb + tid] * 128.0f;
        int i0 = (int)t;
        if (i0 > IMAX) i0 = IMAX;
        i0s[tid] = i0;
        frs[tid] = t - (float)i0;
    }
    if (tid < 32) cpar[tid] = b2[tid];
    else if (tid < 64) cpar[tid] = eng[tid - 32];
    else if (tid < 96) cpar[tid] = enb[tid - 64];
    __syncthreads();

    int dsr[4], ssr[4], i0r[4];
    float frr[4];
    #pragma unroll
    for (int i = 0; i < 4; ++i) {
        int e = 4 * et + i;
        dsr[i] = dsi[e]; ssr[i] = ssi[e];
        i0r[i] = i0s[e]; frr[i] = frs[e];
    }

    float4 accm[4];
    #pragma unroll
    for (int i = 0; i < 4; ++i) accm[i] = make_float4(0,0,0,0);

    for (int ch = 0; ch < 11; ++ch) {
        const int jc = 64 * ch;
        const int colb = jc + 8 * cg;
        float qa[4][8];
        if (colb < TCOLS) {
            #pragma unroll
            for (int i = 0; i < 4; ++i) {
                const float* t0 = T + (size_t)i0r[i] * TCOLS + colb;
                float4 a0 = *(const float4*)t0;
                float4 a1 = *(const float4*)(t0 + 4);
                float4 b0 = *(const float4*)(t0 + TCOLS);
                float4 b1 = *(const float4*)(t0 + TCOLS + 4);
                const float* pr = Pab + (size_t)dsr[i] * PSTRIDE + colb;
                const float* qr = Pab + (size_t)ssr[i] * PSTRIDE + JP + colb;
                float4 p0 = *(const float4*)pr;
                float4 p1 = *(const float4*)(pr + 4);
                float4 q0 = *(const float4*)qr;
                float4 q1 = *(const float4*)(qr + 4);
                float f = frr[i];
                qa[i][0] = silu(fmaf(f, b0.x - a0.x, a0.x) + p0.x + q0.x);
                qa[i][1] = silu(fmaf(f, b0.y - a0.y, a0.y) + p0.y + q0.y);
                qa[i][2] = silu(fmaf(f, b0.z - a0.z, a0.z) + p0.z + q0.z);
                qa[i][3] = silu(fmaf(f, b0.w - a0.w, a0.w) + p0.w + q0.w);
                qa[i][4] = silu(fmaf(f, b1.x - a1.x, a1.x) + p1.x + q1.x);
                qa[i][5] = silu(fmaf(f, b1.y - a1.y, a1.y) + p1.y + q1.y);
                qa[i][6] = silu(fmaf(f, b1.z - a1.z, a1.z) + p1.z + q1.z);
                qa[i][7] = silu(fmaf(f, b1.w - a1.w, a1.w) + p1.w + q1.w);
            }
        } else {
            #pragma unroll
            for (int i = 0; i < 4; ++i)
                #pragma unroll
                for (int c = 0; c < 8; ++c) qa[i][c] = 0.f;
        }

        // ---- phase 2: 2 passes of 32 j ----
        #pragma unroll
        for (int p = 0; p < 2; ++p) {
            __syncthreads();   // Zs free (previous pass / previous chunk reads done)
            if ((cg >> 2) == p) {
                int jl = 8 * (cg & 3);
                #pragma unroll
                for (int jj = 0; jj < 8; ++jj) {
                    *(float4*)&Zs[(jl + jj) * 132 + 4 * et] =
                        make_float4(qa[0][jj], qa[1][jj], qa[2][jj], qa[3][jj]);
                }
            }
            {   // stage W2s rows (jc + 32p + r), all < 768
                int r = tid >> 3, q = tid & 7;
                *(float4*)&W2s[r * 36 + 4 * q] = *(const float4*)(W2p + (size_t)(jc + 32 * p + r) * 32 + 4 * q);
            }
            __syncthreads();
            #pragma unroll 4
            for (int kk = 0; kk < 32; ++kk) {
                float4 z4 = *(const float4*)&Zs[kk * 132 + 4 * eg];
                float4 w4 = *(const float4*)&W2s[kk * 36 + 4 * cq];
                accm[0] = f4fma(z4.x, w4, accm[0]);
                accm[1] = f4fma(z4.y, w4, accm[1]);
                accm[2] = f4fma(z4.z, w4, accm[2]);
                accm[3] = f4fma(z4.w, w4, accm[3]);
            }
        }
    }

    // ---- epilogue: m2 = silu(accm + b2), LN, scatter ----
    __syncthreads();
    {
        float4 bb2 = *(const float4*)&cpar[4 * cq];
        #pragma unroll
        for (int i = 0; i < 4; ++i) {
            int e = 4 * eg + i;
            m2s[e * 36 + 4 * cq + 0] = silu(accm[i].x + bb2.x);
            m2s[e * 36 + 4 * cq + 1] = silu(accm[i].y + bb2.y);
            m2s[e * 36 + 4 * cq + 2] = silu(accm[i].z + bb2.z);
            m2s[e * 36 + 4 * cq + 3] = silu(accm[i].w + bb2.w);
        }
    }
    __syncthreads();
    if (tid < EPB) {
        float s = 0.f, ss = 0.f;
        float v[32];
        #pragma unroll
        for (int c = 0; c < 32; ++c) {
            float x = m2s[tid * 36 + c];
            v[c] = x; s += x; ss += x * x;
        }
        float mean = s * 0.03125f;
        float var = ss * 0.03125f - mean * mean;
        float rstd = 1.0f / sqrtf(var + EPS);
        int d = dsi[tid];
        float* Sp = S + (size_t)d * 32;
        #pragma unroll
        for (int c = 0; c < 32; ++c) {
            float y = (v[c] - mean) * rstd * cpar[32 + c] + cpar[64 + c];
            atomicAdd(&Sp[c], y);
        }
        atomicAdd(&cnt[d], 1.0f);
    }
}

// ---------------- node prep: H0 = [LN(feats) | LN(S/cnt)] ----------------
__global__ __launch_bounds__(128) void k_prep(const float* __restrict__ featsk,
                                              const float* __restrict__ S,
                                              const float* __restrict__ cnt,
                                              const float* __restrict__ nn1g,
                                              const float* __restrict__ nn1b,
                                              const float* __restrict__ eng,
                                              const float* __restrict__ enb,
                                              float* __restrict__ H0) {
    int n = blockIdx.x, tid = threadIdx.x;
    __shared__ float red[4];
    float x = featsk[(size_t)n * 768 + tid];
    float s = wave_sum64(x), ss = wave_sum64(x * x);
    if ((tid & 63) == 0) { red[(tid >> 6) * 2] = s; red[(tid >> 6) * 2 + 1] = ss; }
    __syncthreads();
    float S1 = red[0] + red[2], S2 = red[1] + red[3];
    float mean = S1 * (1.0f / 128.0f);
    float var = S2 * (1.0f / 128.0f) - mean * mean;
    float rstd = 1.0f / sqrtf(var + EPS);
    H0[(size_t)n * 160 + tid] = (x - mean) * rstd * nn1g[tid] + nn1b[tid];
    if (tid < 32) {
        float inv = 1.0f / fmaxf(cnt[n], 1.0f);
        float v = S[(size_t)n * 32 + tid] * inv;
        float s2 = v, q2 = v * v;
        #pragma unroll
        for (int off = 16; off > 0; off >>= 1) {
            s2 += __shfl_xor(s2, off, 64);
            q2 += __shfl_xor(q2, off, 64);
        }
        float m2 = s2 * (1.0f / 32.0f);
        float va = q2 * (1.0f / 32.0f) - m2 * m2;
        float rs = 1.0f / sqrtf(va + EPS);
        H0[(size_t)n * 160 + 128 + tid] = (v - m2) * rs * eng[tid] + enb[tid];
    }
}

// ---------------- LN + residual ----------------
__global__ __launch_bounds__(128) void k_ln_res(const float* __restrict__ H2,
                                                float* __restrict__ feats_all, int k,
                                                const float* __restrict__ g,
                                                const float* __restrict__ b) {
    int n = blockIdx.x, tid = threadIdx.x;
    __shared__ float red[4];
    float x = H2[(size_t)n * 128 + tid];
    float s = wave_sum64(x), ss = wave_sum64(x * x);
    if ((tid & 63) == 0) { red[(tid >> 6) * 2] = s; red[(tid >> 6) * 2 + 1] = ss; }
    __syncthreads();
    float S1 = red[0] + red[2], S2 = red[1] + red[3];
    float mean = S1 * (1.0f / 128.0f);
    float var = S2 * (1.0f / 128.0f) - mean * mean;
    float rstd = 1.0f / sqrtf(var + EPS);
    float v = (x - mean) * rstd * g[tid] + b[tid];
    float f = feats_all[(size_t)n * 768 + k * 128 + tid];
    feats_all[(size_t)n * 768 + (k + 1) * 128 + tid] = f + v;
}

// ---------------- graph pooling (batch sorted -> run-length accum) ----------------
__global__ __launch_bounds__(256) void k_pool(const float* __restrict__ F,
                                              const int* __restrict__ batch,
                                              float* __restrict__ G,
                                              float* __restrict__ cntg) {
    __shared__ int bL[32];
    int b0 = blockIdx.x * 32;
    int tid = threadIdx.x;
    int nmax = min(32, N_NODES - b0);
    if (nmax <= 0) return;
    if (tid < nmax) bL[tid] = batch[b0 + tid];
    __syncthreads();
    float accv = 0.f;
    int cur = -1;
    for (int i = 0; i < nmax; ++i) {
        int g = bL[i];
        if (g != cur) {
            if (cur >= 0) atomicAdd(&G[(size_t)cur * 256 + tid], accv);
            cur = g; accv = 0.f;
        }
        accv += F[(size_t)(b0 + i) * 256 + tid];
    }
    if (cur >= 0) atomicAdd(&G[(size_t)cur * 256 + tid], accv);
    if (tid == 0)
        for (int i = 0; i < nmax; ++i) atomicAdd(&cntg[bL[i]], 1.0f);
}

// ---------------- per-graph MLP head ----------------
__global__ __launch_bounds__(256) void k_graph(const float* __restrict__ G,
                                               const float* __restrict__ cntg,
                                               const float* __restrict__ g1W,
                                               const float* __restrict__ g1b,
                                               const float* __restrict__ g2W,
                                               const float* __restrict__ g2b,
                                               const float* __restrict__ g3W,
                                               const float* __restrict__ g3b,
                                               float* __restrict__ out) {
    __shared__ float X[256], Y[256], red[4];
    int g = blockIdx.x, tid = threadIdx.x;
    float inv = 1.0f / fmaxf(cntg[g], 1.0f);
    X[tid] = G[(size_t)g * 256 + tid] * inv;
    __syncthreads();
    float a = g1b[tid];
    for (int j = 0; j < 256; ++j) a = fmaf(X[j], g1W[(size_t)j * 256 + tid], a);
    Y[tid] = silu(a);
    __syncthreads();
    a = g2b[tid];
    for (int j = 0; j < 256; ++j) a = fmaf(Y[j], g2W[(size_t)j * 256 + tid], a);
    float z = silu(a);
    float p = z * g3W[tid];
    p = wave_sum64(p);
    if ((tid & 63) == 0) red[tid >> 6] = p;
    __syncthreads();
    if (tid == 0) out[g] = red[0] + red[1] + red[2] + red[3] + g3b[0];
}

extern "C" void kernel_launch(void* const* d_in, const int* in_sizes, int n_in,
                              void* d_out, int out_size, void* d_ws, size_t ws_size,
                              hipStream_t stream) {
    const int*   atomids = (const int*)d_in[0];
    const float* coords  = (const float*)d_in[1];
    const int*   eidx    = (const int*)d_in[2];
    const int*   batch   = (const int*)d_in[3];
    const float* emb_w   = (const float*)d_in[4];
    const float* eW1     = (const float*)d_in[5];
    const float* eb1     = (const float*)d_in[6];
    const float* eW2     = (const float*)d_in[7];
    const float* eb2     = (const float*)d_in[8];
    const float* en_g    = (const float*)d_in[9];
    const float* en_b    = (const float*)d_in[10];
    const float* nn1_g   = (const float*)d_in[11];
    const float* nn1_b   = (const float*)d_in[12];
    const float* nW1     = (const float*)d_in[13];
    const float* nb1     = (const float*)d_in[14];
    const float* nW2     = (const float*)d_in[15];
    const float* nb2     = (const float*)d_in[16];
    const float* nn2_g   = (const float*)d_in[17];
    const float* nn2_b   = (const float*)d_in[18];
    const float* f1W     = (const float*)d_in[19];
    const float* f1b     = (const float*)d_in[20];
    const float* f2W     = (const float*)d_in[21];
    const float* f2b     = (const float*)d_in[22];
    const float* f3W     = (const float*)d_in[23];
    const float* f3b     = (const float*)d_in[24];
    const float* g1W     = (const float*)d_in[25];
    const float* g1b     = (const float*)d_in[26];
    const float* g2W     = (const float*)d_in[27];
    const float* g2b     = (const float*)d_in[28];
    const float* g3W     = (const float*)d_in[29];
    const float* g3b     = (const float*)d_in[30];
    float* out = (float*)d_out;

    float* ws = (float*)d_ws;
    // layout (float indices, all multiples of 4 -> 16B aligned); total ~33.7M floats ~= 134.8 MB
    float* feats_all = ws;                        // [10000][768]
    float* d2g   = ws + 7680000;                  // [160000]
    float* Pab   = ws + 7840000;                  // [10000][1536]
    float* S     = ws + 23200000;                 // [10000][32]
    float* cnt   = ws + 23520000;                 // [10000]
    float* W1ab5 = ws + 23530000;                 // [5][128][1536]
    float* W1cp5 = ws + 24513040;                 // [5][65][768]
    float* b1p5  = ws + 24762640;                 // [5][768]
    float* W2p5  = ws + 24766480;                 // [5][768][32]
    float* feG   = ws + 24889360;                 // [12289][68]
    float* T     = ws + 25725012;                 // [12289][648]
    float* G     = ws + 33688284;                 // [64][256]
    float* cntg  = ws + 33704668;                 // [64]
    // node-phase temporaries overlay Pab (dead between phases)
    float* H0 = Pab;                              // [10000][160]
    float* H1 = Pab + 1600000;                    // [10000][256]
    float* H2 = Pab + 4160000;                    // [10000][128]
    float* F1 = Pab;                              // [10000][256]
    float* F2 = Pab + 2560000;                    // [10000][256]
    float* F3 = Pab + 5120000;                    // [10000][256]

    k_embed<<<N_NODES, 128, 0, stream>>>(atomids, emb_w, feats_all);
    k_d2<<<(N_EDGES + 255) / 256, 256, 0, stream>>>(coords, eidx, d2g);
    k_feg<<<(TROWS + 255) / 256, 256, 0, stream>>>(feG);
    k_w1ab5<<<dim3(768, 5), 256, 0, stream>>>(eW1, W1ab5);
    k_wpre5<<<dim3(294, 5), 256, 0, stream>>>(eW1, eb1, eW2, W1cp5, b1p5, W2p5);

    for (int k = 0; k < NK; ++k) {
        const float* eb2k = eb2 + (size_t)k * 32;
        const float* engk = en_g + (size_t)k * 32;
        const float* enbk = en_b + (size_t)k * 32;
        const float* nn1gk = nn1_g + (size_t)k * 128;
        const float* nn1bk = nn1_b + (size_t)k * 128;
        const float* nW1k = nW1 + (size_t)k * 160 * 256;
        const float* nb1k = nb1 + (size_t)k * 256;
        const float* nW2k = nW2 + (size_t)k * 256 * 128;
        const float* nb2k = nb2 + (size_t)k * 128;
        const float* nn2gk = nn2_g + (size_t)k * 128;
        const float* nn2bk = nn2_b + (size_t)k * 128;

        k_tab<<<(TROWS + 31) / 32, 256, 0, stream>>>(feG,
                                                     W1cp5 + (size_t)k * 65 * 768,
                                                     b1p5 + (size_t)k * 768, T);
        k_gemm<<<dim3(79, 12), 256, 0, stream>>>(feats_all + k * 128, 768,
                                                 W1ab5 + (size_t)k * 128 * 1536, 1536,
                                                 nullptr, Pab, 1536, N_NODES, 1536, 128, 0, 0);
        hipMemsetAsync(S, 0, (size_t)330000 * sizeof(float), stream);
        k_edge<<<N_EDGES / EPB, 256, 0, stream>>>(d2g, T, Pab, eidx,
                                                  W2p5 + (size_t)k * 768 * 32,
                                                  eb2k, engk, enbk, S, cnt);
        k_prep<<<N_NODES, 128, 0, stream>>>(feats_all + k * 128, S, cnt,
                                            nn1gk, nn1bk, engk, enbk, H0);
        k_gemm<<<dim3(79, 2), 256, 0, stream>>>(H0, 160, nW1k, 256, nb1k, H1, 256,
                                                N_NODES, 256, 160, 0, 1);
        k_gemm<<<dim3(79, 1), 256, 0, stream>>>(H1, 256, nW2k, 128, nb2k, H2, 128,
                                                N_NODES, 128, 256, 0, 0);
        k_ln_res<<<N_NODES, 128, 0, stream>>>(H2, feats_all, k, nn2gk, nn2bk);
    }

    // final node MLP (F1/F2/F3 overlay Pab)
    k_gemm<<<dim3(79, 2), 256, 0, stream>>>(feats_all, 768, f1W, 256, f1b, F1, 256,
                                            N_NODES, 256, 768, 1, 1);
    k_gemm<<<dim3(79, 2), 256, 0, stream>>>(F1, 256, f2W, 256, f2b, F2, 256,
                                            N_NODES, 256, 256, 0, 1);
    k_gemm<<<dim3(79, 2), 256, 0, stream>>>(F2, 256, f3W, 256, f3b, F3, 256,
                                            N_NODES, 256, 256, 0, 1);

    hipMemsetAsync(G, 0, (size_t)(16384 + 64) * sizeof(float), stream);
    k_pool<<<313, 256, 0, stream>>>(F3, batch, G, cntg);
    k_graph<<<N_GRAPHS, 256, 0, stream>>>(G, cntg, g1W, g1b, g2W, g2b, g3W, g3b, out);
}

// Round 10
// 3718.823 us; speedup vs baseline: 2.2758x; 1.0822x over previous
//
#include <hip/hip_runtime.h>
#include <hip/hip_bf16.h>

#define N_NODES 10000
#define N_EDGES 160000
#define N_GRAPHS 64
#define NK 5
#define EPS 1e-5f
#define EPB 64           // edges per block (128 threads)
#define JP 768           // padded width for Pab halves
#define PSTRIDE 1536     // Pab row stride: [Pa 768 | Pb 768]
#define TCOLS 648        // table row width (642 -> 648)
#define TROWS 12289      // d2 grid [0,96], h=1/128
#define IMAX 12287

__device__ __forceinline__ float silu(float x) { return x / (1.0f + __expf(-x)); }
__device__ __forceinline__ float4 f4fma(float s, float4 w, float4 a) {
    a.x = fmaf(s, w.x, a.x); a.y = fmaf(s, w.y, a.y);
    a.z = fmaf(s, w.z, a.z); a.w = fmaf(s, w.w, a.w);
    return a;
}
__device__ __forceinline__ float wave_sum64(float v) {
    #pragma unroll
    for (int off = 32; off > 0; off >>= 1) v += __shfl_xor(v, off, 64);
    return v;
}

// ---------------- embedding ----------------
__global__ __launch_bounds__(128) void k_embed(const int* __restrict__ atomids,
                                               const float* __restrict__ emb_w,
                                               float* __restrict__ feats_all) {
    int n = blockIdx.x, tid = threadIdx.x;
    feats_all[(size_t)n * 768 + tid] = emb_w[(size_t)atomids[n] * 128 + tid];
}

// ---------------- per-edge squared distance ----------------
__global__ __launch_bounds__(256) void k_d2(const float* __restrict__ coords,
                                            const int* __restrict__ eidx,
                                            float* __restrict__ d2g) {
    int e = blockIdx.x * 256 + threadIdx.x;
    if (e >= N_EDGES) return;
    int s = eidx[e], d = eidx[N_EDGES + e];
    float dx = coords[s * 3 + 0] - coords[d * 3 + 0];
    float dy = coords[s * 3 + 1] - coords[d * 3 + 1];
    float dz = coords[s * 3 + 2] - coords[d * 3 + 2];
    d2g[e] = dx * dx + dy * dy + dz * dz;
}

// ---------------- in-degree (layer-invariant, computed once) ----------------
__global__ __launch_bounds__(256) void k_cnt(const int* __restrict__ eidx,
                                             float* __restrict__ cnt) {
    int e = blockIdx.x * 256 + threadIdx.x;
    if (e >= N_EDGES) return;
    atomicAdd(&cnt[eidx[N_EDGES + e]], 1.0f);
}

// ---------------- fourier features on the d2 GRID (once; layer-independent) ----------------
__global__ __launch_bounds__(256) void k_feg(float* __restrict__ feG) {  // [TROWS][68]
    int g = blockIdx.x * 256 + threadIdx.x;
    if (g >= TROWS) return;
    float d2v = (float)g * 0.0078125f;   // g / 128, exact
    float* o = feG + (size_t)g * 68;
    float sc = 1.0f;
    #pragma unroll
    for (int i = 0; i < 32; ++i) {
        float x = d2v * sc;
        o[i] = sinf(x);
        o[32 + i] = cosf(x);
        sc *= 0.5f;
    }
    o[64] = d2v;
}

// ---------------- per-layer q-table: T[g][j] = fe(g/128) @ W1c + b1 ----------------
__global__ __launch_bounds__(256) void k_tab(const float* __restrict__ feG,   // [TROWS][68]
                                             const float* __restrict__ W1cp,  // [65][768] padded
                                             const float* __restrict__ b1p,   // [768] padded
                                             float* __restrict__ T) {         // [TROWS][648]
    __shared__ float feGs[32 * 68];
    __shared__ float W1s[65 * 36];
    const int tid = threadIdx.x;
    const int g0 = blockIdx.x * 32;
    for (int idx = tid; idx < 32 * 17; idx += 256) {
        int r = idx / 17, c = idx - r * 17;
        int gi = g0 + r;
        float4 v = make_float4(0, 0, 0, 0);
        if (gi < TROWS) v = *(const float4*)(feG + (size_t)gi * 68 + 4 * c);
        *(float4*)&feGs[r * 68 + 4 * c] = v;
    }
    const int gt = tid >> 3, ct = tid & 7;
    for (int jc = 0; jc < TCOLS; jc += 32) {
        __syncthreads();
        for (int idx = tid; idx < 65 * 32; idx += 256) {
            int k = idx >> 5, j = idx & 31;
            W1s[k * 36 + j] = W1cp[(size_t)k * 768 + jc + j];
        }
        __syncthreads();
        int gj = jc + 4 * ct;
        float4 q = *(const float4*)(b1p + gj);
        #pragma unroll 5
        for (int k = 0; k < 65; ++k) {
            float f = feGs[gt * 68 + k];
            float4 w = *(const float4*)&W1s[k * 36 + 4 * ct];
            q = f4fma(f, w, q);
        }
        int g = g0 + gt;
        if (g < TROWS && gj < TCOLS)
            *(float4*)(T + (size_t)g * TCOLS + gj) = q;
    }
}

// ---------------- W1ab prestage, all 5 layers: [5][128][1536] ----------------
__global__ __launch_bounds__(256) void k_w1ab5(const float* __restrict__ eW1,
                                               float* __restrict__ W1ab5) {
    int k = blockIdx.y;
    const float* W1 = eW1 + (size_t)k * 321 * 642;
    float* W1ab = W1ab5 + (size_t)k * 128 * 1536;
    int idx = blockIdx.x * 256 + threadIdx.x;
    if (idx >= 128 * 1536) return;
    int r = idx / 1536;
    int j = idx - r * 1536;
    float v = 0.f;
    if (j < 642) v = W1[(size_t)r * 642 + j];
    else if (j >= 768 && j < 1410) v = W1[(size_t)(128 + r) * 642 + (j - 768)];
    W1ab[idx] = v;
}

// ---------------- padded edge-weight prestage (all 5 layers) ----------------
__global__ __launch_bounds__(256) void k_wpre5(const float* __restrict__ eW1,
                                               const float* __restrict__ eb1,
                                               const float* __restrict__ eW2,
                                               float* __restrict__ W1cp5,   // [5][65][768]
                                               float* __restrict__ b1p5,    // [5][768]
                                               float* __restrict__ W2p5) {  // [5][768][32]
    int k = blockIdx.y;
    const float* W1 = eW1 + (size_t)k * 321 * 642;
    const float* b1 = eb1 + (size_t)k * 642;
    const float* W2 = eW2 + (size_t)k * 642 * 32;
    float* W1cp = W1cp5 + (size_t)k * 65 * 768;
    float* b1p  = b1p5 + (size_t)k * 768;
    float* W2p  = W2p5 + (size_t)k * 768 * 32;
    int idx = blockIdx.x * 256 + threadIdx.x;
    if (idx < 65 * 768) {
        int r = idx / 768, j = idx - r * 768;
        W1cp[idx] = (j < 642) ? W1[(size_t)(256 + r) * 642 + j] : 0.f;
    } else if (idx < 65 * 768 + 768) {
        int j = idx - 65 * 768;
        b1p[j] = (j < 642) ? b1[j] : 0.f;
    } else if (idx < 65 * 768 + 768 + 768 * 32) {
        int t = idx - (65 * 768 + 768);
        int j = t >> 5, c = t & 31;
        W2p[t] = (j < 642) ? W2[(size_t)j * 32 + c] : 0.f;
    }
}

// ---------------- fp32 GEMM: C = act(actA(A)[M][K] @ B[K][N] + bias) ----------------
__global__ __launch_bounds__(256) void k_gemm(const float* __restrict__ A, int lda,
                                              const float* __restrict__ B, int ldb,
                                              const float* __restrict__ bias,
                                              float* __restrict__ C, int ldc,
                                              int M, int N, int K, int siluA, int siluOut) {
    __shared__ float As[32 * 132];
    __shared__ float Bs[32 * 132];
    const int tid = threadIdx.x;
    const int m0 = blockIdx.x * 128, n0 = blockIdx.y * 128;
    const int tm = tid >> 4, tn = tid & 15;

    float4 acc[8][2];
    #pragma unroll
    for (int r = 0; r < 8; ++r) { acc[r][0] = make_float4(0,0,0,0); acc[r][1] = make_float4(0,0,0,0); }

    for (int kc = 0; kc < K; kc += 32) {
        #pragma unroll
        for (int i = 0; i < 4; ++i) {
            int idx = tid + i * 256;
            int m = idx >> 3, kq = idx & 7;
            int gm = m0 + m;
            int cm = (gm < M) ? gm : (M - 1);
            float4 a = *(const float4*)(A + (size_t)cm * lda + kc + 4 * kq);
            if (gm >= M) a = make_float4(0,0,0,0);
            if (siluA) { a.x = silu(a.x); a.y = silu(a.y); a.z = silu(a.z); a.w = silu(a.w); }
            As[(4 * kq + 0) * 132 + m] = a.x;
            As[(4 * kq + 1) * 132 + m] = a.y;
            As[(4 * kq + 2) * 132 + m] = a.z;
            As[(4 * kq + 3) * 132 + m] = a.w;
        }
        #pragma unroll
        for (int i = 0; i < 4; ++i) {
            int idx = tid + i * 256;
            int r = idx >> 5, cq = idx & 31;
            int gn = n0 + 4 * cq;
            float4 b = make_float4(0,0,0,0);
            if (gn < N) b = *(const float4*)(B + (size_t)(kc + r) * ldb + gn);
            *(float4*)&Bs[r * 132 + 4 * cq] = b;
        }
        __syncthreads();
        #pragma unroll 4
        for (int kk = 0; kk < 32; ++kk) {
            float4 a0 = *(const float4*)&As[kk * 132 + 8 * tm];
            float4 a1 = *(const float4*)&As[kk * 132 + 8 * tm + 4];
            float4 b0 = *(const float4*)&Bs[kk * 132 + 4 * tn];
            float4 b1 = *(const float4*)&Bs[kk * 132 + 64 + 4 * tn];
            acc[0][0] = f4fma(a0.x, b0, acc[0][0]); acc[0][1] = f4fma(a0.x, b1, acc[0][1]);
            acc[1][0] = f4fma(a0.y, b0, acc[1][0]); acc[1][1] = f4fma(a0.y, b1, acc[1][1]);
            acc[2][0] = f4fma(a0.z, b0, acc[2][0]); acc[2][1] = f4fma(a0.z, b1, acc[2][1]);
            acc[3][0] = f4fma(a0.w, b0, acc[3][0]); acc[3][1] = f4fma(a0.w, b1, acc[3][1]);
            acc[4][0] = f4fma(a1.x, b0, acc[4][0]); acc[4][1] = f4fma(a1.x, b1, acc[4][1]);
            acc[5][0] = f4fma(a1.y, b0, acc[5][0]); acc[5][1] = f4fma(a1.y, b1, acc[5][1]);
            acc[6][0] = f4fma(a1.z, b0, acc[6][0]); acc[6][1] = f4fma(a1.z, b1, acc[6][1]);
            acc[7][0] = f4fma(a1.w, b0, acc[7][0]); acc[7][1] = f4fma(a1.w, b1, acc[7][1]);
        }
        __syncthreads();
    }

    const int gnl = n0 + 4 * tn, gnh = n0 + 64 + 4 * tn;
    #pragma unroll
    for (int r = 0; r < 8; ++r) {
        int gm = m0 + 8 * tm + r;
        if (gm >= M) continue;
        float4 v0 = acc[r][0], v1 = acc[r][1];
        if (gnl < N) {
            if (bias) { v0.x += bias[gnl+0]; v0.y += bias[gnl+1]; v0.z += bias[gnl+2]; v0.w += bias[gnl+3]; }
            if (siluOut) { v0.x = silu(v0.x); v0.y = silu(v0.y); v0.z = silu(v0.z); v0.w = silu(v0.w); }
            *(float4*)&C[(size_t)gm * ldc + gnl] = v0;
        }
        if (gnh < N) {
            if (bias) { v1.x += bias[gnh+0]; v1.y += bias[gnh+1]; v1.z += bias[gnh+2]; v1.w += bias[gnh+3]; }
            if (siluOut) { v1.x = silu(v1.x); v1.y = silu(v1.y); v1.z = silu(v1.z); v1.w = silu(v1.w); }
            *(float4*)&C[(size_t)gm * ldc + gnh] = v1;
        }
    }
}

// ---------------- fused edge kernel: table-lerp phase-1, Zs phase-2 ----------------
// 64 edges/block, 128 threads, 11 chunks of 64 cols.
// Phase1 (et=tid&15: 4 edges, cg=tid>>4: 8 cols): q = lerp(T) + Pa[dst] + Pb[src]; z=silu(q).
// Phase2 (eg=tid>>3: 4 edges, cq=tid&7: 4 cols): 2 passes of 32 j via Zs; accm = 4 x float4.
// NOTE: Pab columns up to 1471 are read -> the Pab GEMM must write all 1536 columns
// (zero-padded W1ab makes cols 642..767 / 1410..1535 true zeros). Do NOT trim N below 1536.
__global__ __launch_bounds__(128) void k_edge(const float* __restrict__ d2g,
                                              const float* __restrict__ T,     // [TROWS][648]
                                              const float* __restrict__ Pab,   // [N_NODES][1536]
                                              const int* __restrict__ eidx,
                                              const float* __restrict__ W2p,   // [768][32]
                                              const float* __restrict__ b2,
                                              const float* __restrict__ eng,
                                              const float* __restrict__ enb,
                                              float* __restrict__ S) {
    __shared__ float U[3392];            // Zs[32][68]=2176 | W2s[32][36]=1152; overlay m2s[64][36]=2304
    __shared__ int dsi[EPB], ssi[EPB], i0s[EPB];
    __shared__ float frs[EPB];
    __shared__ float cpar[96];
    float* Zs  = U;
    float* W2s = U + 2176;
    float* m2s = U;

    const int tid = threadIdx.x;
    const int eb = blockIdx.x * EPB;
    const int et = tid & 15, cg = tid >> 4;   // phase-1: edges 4*et.., cols 8*cg..
    const int eg = tid >> 3, cq = tid & 7;    // phase-2: edges 4*eg.., cols 4*cq..

    if (tid < EPB) {
        ssi[tid] = eidx[eb + tid];
        dsi[tid] = eidx[N_EDGES + eb + tid];
        float t = d2g[eb + tid] * 128.0f;
        int i0 = (int)t;
        if (i0 > IMAX) i0 = IMAX;
        i0s[tid] = i0;
        frs[tid] = t - (float)i0;
    }
    if (tid < 32) cpar[tid] = b2[tid];
    else if (tid < 64) cpar[tid] = eng[tid - 32];
    else if (tid < 96) cpar[tid] = enb[tid - 64];
    __syncthreads();

    int dsr[4], ssr[4], i0r[4];
    float frr[4];
    #pragma unroll
    for (int i = 0; i < 4; ++i) {
        int e = 4 * et + i;
        dsr[i] = dsi[e]; ssr[i] = ssi[e];
        i0r[i] = i0s[e]; frr[i] = frs[e];
    }

    float4 accm[4];
    #pragma unroll
    for (int i = 0; i < 4; ++i) accm[i] = make_float4(0,0,0,0);

    for (int ch = 0; ch < 11; ++ch) {
        const int jc = 64 * ch;
        const int colb = jc + 8 * cg;
        float qa[4][8];
        if (colb < TCOLS) {
            #pragma unroll
            for (int i = 0; i < 4; ++i) {
                const float* t0 = T + (size_t)i0r[i] * TCOLS + colb;
                float4 a0 = *(const float4*)t0;
                float4 a1 = *(const float4*)(t0 + 4);
                float4 b0 = *(const float4*)(t0 + TCOLS);
                float4 b1 = *(const float4*)(t0 + TCOLS + 4);
                const float* pr = Pab + (size_t)dsr[i] * PSTRIDE + colb;
                const float* qr = Pab + (size_t)ssr[i] * PSTRIDE + JP + colb;
                float4 p0 = *(const float4*)pr;
                float4 p1 = *(const float4*)(pr + 4);
                float4 q0 = *(const float4*)qr;
                float4 q1 = *(const float4*)(qr + 4);
                float f = frr[i];
                qa[i][0] = silu(fmaf(f, b0.x - a0.x, a0.x) + p0.x + q0.x);
                qa[i][1] = silu(fmaf(f, b0.y - a0.y, a0.y) + p0.y + q0.y);
                qa[i][2] = silu(fmaf(f, b0.z - a0.z, a0.z) + p0.z + q0.z);
                qa[i][3] = silu(fmaf(f, b0.w - a0.w, a0.w) + p0.w + q0.w);
                qa[i][4] = silu(fmaf(f, b1.x - a1.x, a1.x) + p1.x + q1.x);
                qa[i][5] = silu(fmaf(f, b1.y - a1.y, a1.y) + p1.y + q1.y);
                qa[i][6] = silu(fmaf(f, b1.z - a1.z, a1.z) + p1.z + q1.z);
                qa[i][7] = silu(fmaf(f, b1.w - a1.w, a1.w) + p1.w + q1.w);
            }
        } else {
            #pragma unroll
            for (int i = 0; i < 4; ++i)
                #pragma unroll
                for (int c = 0; c < 8; ++c) qa[i][c] = 0.f;
        }

        // ---- phase 2: 2 passes of 32 j ----
        #pragma unroll
        for (int p = 0; p < 2; ++p) {
            __syncthreads();   // Zs free
            if ((cg >> 2) == p) {
                int jl = 8 * (cg & 3);
                #pragma unroll
                for (int jj = 0; jj < 8; ++jj) {
                    *(float4*)&Zs[(jl + jj) * 68 + 4 * et] =
                        make_float4(qa[0][jj], qa[1][jj], qa[2][jj], qa[3][jj]);
                }
            }
            #pragma unroll
            for (int i = 0; i < 2; ++i) {   // stage W2s rows (jc + 32p + r)
                int idx = tid + i * 128;
                int r = idx >> 3, q = idx & 7;
                *(float4*)&W2s[r * 36 + 4 * q] = *(const float4*)(W2p + (size_t)(jc + 32 * p + r) * 32 + 4 * q);
            }
            __syncthreads();
            #pragma unroll 4
            for (int kk = 0; kk < 32; ++kk) {
                float4 z4 = *(const float4*)&Zs[kk * 68 + 4 * eg];
                float4 w4 = *(const float4*)&W2s[kk * 36 + 4 * cq];
                accm[0] = f4fma(z4.x, w4, accm[0]);
                accm[1] = f4fma(z4.y, w4, accm[1]);
                accm[2] = f4fma(z4.z, w4, accm[2]);
                accm[3] = f4fma(z4.w, w4, accm[3]);
            }
        }
    }

    // ---- epilogue: m2 = silu(accm + b2), LN, scatter ----
    __syncthreads();
    {
        float4 bb2 = *(const float4*)&cpar[4 * cq];
        #pragma unroll
        for (int i = 0; i < 4; ++i) {
            int e = 4 * eg + i;
            m2s[e * 36 + 4 * cq + 0] = silu(accm[i].x + bb2.x);
            m2s[e * 36 + 4 * cq + 1] = silu(accm[i].y + bb2.y);
            m2s[e * 36 + 4 * cq + 2] = silu(accm[i].z + bb2.z);
            m2s[e * 36 + 4 * cq + 3] = silu(accm[i].w + bb2.w);
        }
    }
    __syncthreads();
    if (tid < EPB) {
        float s = 0.f, ss = 0.f;
        float v[32];
        #pragma unroll
        for (int c = 0; c < 32; ++c) {
            float x = m2s[tid * 36 + c];
            v[c] = x; s += x; ss += x * x;
        }
        float mean = s * 0.03125f;
        float var = ss * 0.03125f - mean * mean;
        float rstd = 1.0f / sqrtf(var + EPS);
        int d = dsi[tid];
        float* Sp = S + (size_t)d * 32;
        #pragma unroll
        for (int c = 0; c < 32; ++c) {
            float y = (v[c] - mean) * rstd * cpar[32 + c] + cpar[64 + c];
            atomicAdd(&Sp[c], y);
        }
    }
}

// ---------------- node prep: H0 = [LN(feats) | LN(S/cnt)] ----------------
__global__ __launch_bounds__(128) void k_prep(const float* __restrict__ featsk,
                                              const float* __restrict__ S,
                                              const float* __restrict__ cnt,
                                              const float* __restrict__ nn1g,
                                              const float* __restrict__ nn1b,
                                              const float* __restrict__ eng,
                                              const float* __restrict__ enb,
                                              float* __restrict__ H0) {
    int n = blockIdx.x, tid = threadIdx.x;
    __shared__ float red[4];
    float x = featsk[(size_t)n * 768 + tid];
    float s = wave_sum64(x), ss = wave_sum64(x * x);
    if ((tid & 63) == 0) { red[(tid >> 6) * 2] = s; red[(tid >> 6) * 2 + 1] = ss; }
    __syncthreads();
    float S1 = red[0] + red[2], S2 = red[1] + red[3];
    float mean = S1 * (1.0f / 128.0f);
    float var = S2 * (1.0f / 128.0f) - mean * mean;
    float rstd = 1.0f / sqrtf(var + EPS);
    H0[(size_t)n * 160 + tid] = (x - mean) * rstd * nn1g[tid] + nn1b[tid];
    if (tid < 32) {
        float inv = 1.0f / fmaxf(cnt[n], 1.0f);
        float v = S[(size_t)n * 32 + tid] * inv;
        float s2 = v, q2 = v * v;
        #pragma unroll
        for (int off = 16; off > 0; off >>= 1) {
            s2 += __shfl_xor(s2, off, 64);
            q2 += __shfl_xor(q2, off, 64);
        }
        float m2 = s2 * (1.0f / 32.0f);
        float va = q2 * (1.0f / 32.0f) - m2 * m2;
        float rs = 1.0f / sqrtf(va + EPS);
        H0[(size_t)n * 160 + 128 + tid] = (v - m2) * rs * eng[tid] + enb[tid];
    }
}

// ---------------- LN + residual ----------------
__global__ __launch_bounds__(128) void k_ln_res(const float* __restrict__ H2,
                                                float* __restrict__ feats_all, int k,
                                                const float* __restrict__ g,
                                                const float* __restrict__ b) {
    int n = blockIdx.x, tid = threadIdx.x;
    __shared__ float red[4];
    float x = H2[(size_t)n * 128 + tid];
    float s = wave_sum64(x), ss = wave_sum64(x * x);
    if ((tid & 63) == 0) { red[(tid >> 6) * 2] = s; red[(tid >> 6) * 2 + 1] = ss; }
    __syncthreads();
    float S1 = red[0] + red[2], S2 = red[1] + red[3];
    float mean = S1 * (1.0f / 128.0f);
    float var = S2 * (1.0f / 128.0f) - mean * mean;
    float rstd = 1.0f / sqrtf(var + EPS);
    float v = (x - mean) * rstd * g[tid] + b[tid];
    float f = feats_all[(size_t)n * 768 + k * 128 + tid];
    feats_all[(size_t)n * 768 + (k + 1) * 128 + tid] = f + v;
}

// ---------------- graph pooling (batch sorted -> run-length accum) ----------------
__global__ __launch_bounds__(256) void k_pool(const float* __restrict__ F,
                                              const int* __restrict__ batch,
                                              float* __restrict__ G,
                                              float* __restrict__ cntg) {
    __shared__ int bL[32];
    int b0 = blockIdx.x * 32;
    int tid = threadIdx.x;
    int nmax = min(32, N_NODES - b0);
    if (nmax <= 0) return;
    if (tid < nmax) bL[tid] = batch[b0 + tid];
    __syncthreads();
    float accv = 0.f;
    int cur = -1;
    for (int i = 0; i < nmax; ++i) {
        int g = bL[i];
        if (g != cur) {
            if (cur >= 0) atomicAdd(&G[(size_t)cur * 256 + tid], accv);
            cur = g; accv = 0.f;
        }
        accv += F[(size_t)(b0 + i) * 256 + tid];
    }
    if (cur >= 0) atomicAdd(&G[(size_t)cur * 256 + tid], accv);
    if (tid == 0)
        for (int i = 0; i < nmax; ++i) atomicAdd(&cntg[bL[i]], 1.0f);
}

// ---------------- per-graph MLP head ----------------
__global__ __launch_bounds__(256) void k_graph(const float* __restrict__ G,
                                               const float* __restrict__ cntg,
                                               const float* __restrict__ g1W,
                                               const float* __restrict__ g1b,
                                               const float* __restrict__ g2W,
                                               const float* __restrict__ g2b,
                                               const float* __restrict__ g3W,
                                               const float* __restrict__ g3b,
                                               float* __restrict__ out) {
    __shared__ float X[256], Y[256], red[4];
    int g = blockIdx.x, tid = threadIdx.x;
    float inv = 1.0f / fmaxf(cntg[g], 1.0f);
    X[tid] = G[(size_t)g * 256 + tid] * inv;
    __syncthreads();
    float a = g1b[tid];
    for (int j = 0; j < 256; ++j) a = fmaf(X[j], g1W[(size_t)j * 256 + tid], a);
    Y[tid] = silu(a);
    __syncthreads();
    a = g2b[tid];
    for (int j = 0; j < 256; ++j) a = fmaf(Y[j], g2W[(size_t)j * 256 + tid], a);
    float z = silu(a);
    float p = z * g3W[tid];
    p = wave_sum64(p);
    if ((tid & 63) == 0) red[tid >> 6] = p;
    __syncthreads();
    if (tid == 0) out[g] = red[0] + red[1] + red[2] + red[3] + g3b[0];
}

extern "C" void kernel_launch(void* const* d_in, const int* in_sizes, int n_in,
                              void* d_out, int out_size, void* d_ws, size_t ws_size,
                              hipStream_t stream) {
    const int*   atomids = (const int*)d_in[0];
    const float* coords  = (const float*)d_in[1];
    const int*   eidx    = (const int*)d_in[2];
    const int*   batch   = (const int*)d_in[3];
    const float* emb_w   = (const float*)d_in[4];
    const float* eW1     = (const float*)d_in[5];
    const float* eb1     = (const float*)d_in[6];
    const float* eW2     = (const float*)d_in[7];
    const float* eb2     = (const float*)d_in[8];
    const float* en_g    = (const float*)d_in[9];
    const float* en_b    = (const float*)d_in[10];
    const float* nn1_g   = (const float*)d_in[11];
    const float* nn1_b   = (const float*)d_in[12];
    const float* nW1     = (const float*)d_in[13];
    const float* nb1     = (const float*)d_in[14];
    const float* nW2     = (const float*)d_in[15];
    const float* nb2     = (const float*)d_in[16];
    const float* nn2_g   = (const float*)d_in[17];
    const float* nn2_b   = (const float*)d_in[18];
    const float* f1W     = (const float*)d_in[19];
    const float* f1b     = (const float*)d_in[20];
    const float* f2W     = (const float*)d_in[21];
    const float* f2b     = (const float*)d_in[22];
    const float* f3W     = (const float*)d_in[23];
    const float* f3b     = (const float*)d_in[24];
    const float* g1W     = (const float*)d_in[25];
    const float* g1b     = (const float*)d_in[26];
    const float* g2W     = (const float*)d_in[27];
    const float* g2b     = (const float*)d_in[28];
    const float* g3W     = (const float*)d_in[29];
    const float* g3b     = (const float*)d_in[30];
    float* out = (float*)d_out;

    float* ws = (float*)d_ws;
    float* feats_all = ws;                        // [10000][768]
    float* d2g   = ws + 7680000;                  // [160000]
    float* Pab   = ws + 7840000;                  // [10000][1536]
    float* S     = ws + 23200000;                 // [10000][32]
    float* cnt   = ws + 23520000;                 // [10000]
    float* W1ab5 = ws + 23530000;                 // [5][128][1536]
    float* W1cp5 = ws + 24513040;                 // [5][65][768]
    float* b1p5  = ws + 24762640;                 // [5][768]
    float* W2p5  = ws + 24766480;                 // [5][768][32]
    float* feG   = ws + 24889360;                 // [12289][68]
    float* T     = ws + 25725012;                 // [12289][648]
    float* G     = ws + 33688284;                 // [64][256]
    float* cntg  = ws + 33704668;                 // [64]
    // node-phase temporaries overlay Pab (dead between phases)
    float* H0 = Pab;                              // [10000][160]
    float* H1 = Pab + 1600000;                    // [10000][256]
    float* H2 = Pab + 4160000;                    // [10000][128]
    float* F1 = Pab;                              // [10000][256]
    float* F2 = Pab + 2560000;                    // [10000][256]
    float* F3 = Pab + 5120000;                    // [10000][256]

    k_embed<<<N_NODES, 128, 0, stream>>>(atomids, emb_w, feats_all);
    k_d2<<<(N_EDGES + 255) / 256, 256, 0, stream>>>(coords, eidx, d2g);
    hipMemsetAsync(cnt, 0, 10000 * sizeof(float), stream);
    k_cnt<<<(N_EDGES + 255) / 256, 256, 0, stream>>>(eidx, cnt);
    k_feg<<<(TROWS + 255) / 256, 256, 0, stream>>>(feG);
    k_w1ab5<<<dim3(768, 5), 256, 0, stream>>>(eW1, W1ab5);
    k_wpre5<<<dim3(294, 5), 256, 0, stream>>>(eW1, eb1, eW2, W1cp5, b1p5, W2p5);

    for (int k = 0; k < NK; ++k) {
        const float* eb2k = eb2 + (size_t)k * 32;
        const float* engk = en_g + (size_t)k * 32;
        const float* enbk = en_b + (size_t)k * 32;
        const float* nn1gk = nn1_g + (size_t)k * 128;
        const float* nn1bk = nn1_b + (size_t)k * 128;
        const float* nW1k = nW1 + (size_t)k * 160 * 256;
        const float* nb1k = nb1 + (size_t)k * 256;
        const float* nW2k = nW2 + (size_t)k * 256 * 128;
        const float* nb2k = nb2 + (size_t)k * 128;
        const float* nn2gk = nn2_g + (size_t)k * 128;
        const float* nn2bk = nn2_b + (size_t)k * 128;

        k_tab<<<(TROWS + 31) / 32, 256, 0, stream>>>(feG,
                                                     W1cp5 + (size_t)k * 65 * 768,
                                                     b1p5 + (size_t)k * 768, T);
        // MUST write all 1536 Pab columns (k_edge reads zero-padding up to col 1471)
        k_gemm<<<dim3(79, 12), 256, 0, stream>>>(feats_all + k * 128, 768,
                                                 W1ab5 + (size_t)k * 128 * 1536, 1536,
                                                 nullptr, Pab, 1536, N_NODES, 1536, 128, 0, 0);
        hipMemsetAsync(S, 0, (size_t)320000 * sizeof(float), stream);
        k_edge<<<N_EDGES / EPB, 128, 0, stream>>>(d2g, T, Pab, eidx,
                                                  W2p5 + (size_t)k * 768 * 32,
                                                  eb2k, engk, enbk, S);
        k_prep<<<N_NODES, 128, 0, stream>>>(feats_all + k * 128, S, cnt,
                                            nn1gk, nn1bk, engk, enbk, H0);
        k_gemm<<<dim3(79, 2), 256, 0, stream>>>(H0, 160, nW1k, 256, nb1k, H1, 256,
                                                N_NODES, 256, 160, 0, 1);
        k_gemm<<<dim3(79, 1), 256, 0, stream>>>(H1, 256, nW2k, 128, nb2k, H2, 128,
                                                N_NODES, 128, 256, 0, 0);
        k_ln_res<<<N_NODES, 128, 0, stream>>>(H2, feats_all, k, nn2gk, nn2bk);
    }

    // final node MLP (F1/F2/F3 overlay Pab)
    k_gemm<<<dim3(79, 2), 256, 0, stream>>>(feats_all, 768, f1W, 256, f1b, F1, 256,
                                            N_NODES, 256, 768, 1, 1);
    k_gemm<<<dim3(79, 2), 256, 0, stream>>>(F1, 256, f2W, 256, f2b, F2, 256,
                                            N_NODES, 256, 256, 0, 1);
    k_gemm<<<dim3(79, 2), 256, 0, stream>>>(F2, 256, f3W, 256, f3b, F3, 256,
                                            N_NODES, 256, 256, 0, 1);

    hipMemsetAsync(G, 0, (size_t)(16384 + 64) * sizeof(float), stream);
    k_pool<<<313, 256, 0, stream>>>(F3, batch, G, cntg);
    k_graph<<<N_GRAPHS, 256, 0, stream>>>(G, cntg, g1W, g1b, g2W, g2b, g3W, g3b, out);
}

// Round 11
// 3680.802 us; speedup vs baseline: 2.2994x; 1.0103x over previous
//
#include <hip/hip_runtime.h>
#include <hip/hip_bf16.h>

#define N_NODES 10000
#define N_EDGES 160000
#define N_GRAPHS 64
#define NK 5
#define EPS 1e-5f
#define EPB 64           // edges per block (128 threads)
#define JP 768           // padded width for Pab halves
#define PSTRIDE 1536     // Pab row stride: [Pa 768 | Pb 768]
#define TCOLS 648        // table row width (642 -> 648)
#define TROWS 12289      // d2 grid [0,96], h=1/128
#define IMAX 12287

__device__ __forceinline__ float silu(float x) { return x / (1.0f + __expf(-x)); }
__device__ __forceinline__ float4 f4fma(float s, float4 w, float4 a) {
    a.x = fmaf(s, w.x, a.x); a.y = fmaf(s, w.y, a.y);
    a.z = fmaf(s, w.z, a.z); a.w = fmaf(s, w.w, a.w);
    return a;
}
__device__ __forceinline__ float wave_sum64(float v) {
    #pragma unroll
    for (int off = 32; off > 0; off >>= 1) v += __shfl_xor(v, off, 64);
    return v;
}

// ---------------- embedding ----------------
__global__ __launch_bounds__(128) void k_embed(const int* __restrict__ atomids,
                                               const float* __restrict__ emb_w,
                                               float* __restrict__ feats_all) {
    int n = blockIdx.x, tid = threadIdx.x;
    feats_all[(size_t)n * 768 + tid] = emb_w[(size_t)atomids[n] * 128 + tid];
}

// ---------------- per-edge squared distance ----------------
__global__ __launch_bounds__(256) void k_d2(const float* __restrict__ coords,
                                            const int* __restrict__ eidx,
                                            float* __restrict__ d2g) {
    int e = blockIdx.x * 256 + threadIdx.x;
    if (e >= N_EDGES) return;
    int s = eidx[e], d = eidx[N_EDGES + e];
    float dx = coords[s * 3 + 0] - coords[d * 3 + 0];
    float dy = coords[s * 3 + 1] - coords[d * 3 + 1];
    float dz = coords[s * 3 + 2] - coords[d * 3 + 2];
    d2g[e] = dx * dx + dy * dy + dz * dz;
}

// ---------------- in-degree (layer-invariant) ----------------
__global__ __launch_bounds__(256) void k_cnt(const int* __restrict__ eidx,
                                             float* __restrict__ cnt) {
    int e = blockIdx.x * 256 + threadIdx.x;
    if (e >= N_EDGES) return;
    atomicAdd(&cnt[eidx[N_EDGES + e]], 1.0f);
}

// ---------------- counting sort of edges by i0 (T-row index) ----------------
__global__ __launch_bounds__(256) void k_hist(const float* __restrict__ d2g,
                                              int* __restrict__ hist) {
    int e = blockIdx.x * 256 + threadIdx.x;
    if (e >= N_EDGES) return;
    int i0 = (int)(d2g[e] * 128.0f);
    if (i0 > IMAX) i0 = IMAX;
    atomicAdd(&hist[i0], 1);
}

__global__ __launch_bounds__(256) void k_scan(const int* __restrict__ hist,
                                              int* __restrict__ offs) {
    __shared__ int buf[256];
    __shared__ int carryS;
    int tid = threadIdx.x;
    if (tid == 0) carryS = 0;
    __syncthreads();
    for (int base = 0; base < TROWS; base += 256) {
        int v = (base + tid < TROWS) ? hist[base + tid] : 0;
        buf[tid] = v;
        __syncthreads();
        for (int off = 1; off < 256; off <<= 1) {
            int t = (tid >= off) ? buf[tid - off] : 0;
            __syncthreads();
            buf[tid] += t;
            __syncthreads();
        }
        if (base + tid < TROWS) offs[base + tid] = carryS + buf[tid] - v;  // exclusive
        __syncthreads();
        if (tid == 0) carryS += buf[255];
        __syncthreads();
    }
}

__global__ __launch_bounds__(256) void k_copyi(const int* __restrict__ a,
                                               int* __restrict__ b) {
    int i = blockIdx.x * 256 + threadIdx.x;
    if (i < TROWS) b[i] = a[i];
}

__global__ __launch_bounds__(256) void k_scatter(const int* __restrict__ eidx,
                                                 const float* __restrict__ d2g,
                                                 int* __restrict__ cursor,
                                                 int* __restrict__ ssiP,
                                                 int* __restrict__ dsiP,
                                                 int* __restrict__ i0P,
                                                 float* __restrict__ frP) {
    int e = blockIdx.x * 256 + threadIdx.x;
    if (e >= N_EDGES) return;
    float t = d2g[e] * 128.0f;
    int i0 = (int)t;
    if (i0 > IMAX) i0 = IMAX;
    float fr = t - (float)i0;
    int pos = atomicAdd(&cursor[i0], 1);
    ssiP[pos] = eidx[e];
    dsiP[pos] = eidx[N_EDGES + e];
    i0P[pos] = i0;
    frP[pos] = fr;
}

// ---------------- fourier features on the d2 GRID (once) ----------------
__global__ __launch_bounds__(256) void k_feg(float* __restrict__ feG) {  // [TROWS][68]
    int g = blockIdx.x * 256 + threadIdx.x;
    if (g >= TROWS) return;
    float d2v = (float)g * 0.0078125f;   // g / 128, exact
    float* o = feG + (size_t)g * 68;
    float sc = 1.0f;
    #pragma unroll
    for (int i = 0; i < 32; ++i) {
        float x = d2v * sc;
        o[i] = sinf(x);
        o[32 + i] = cosf(x);
        sc *= 0.5f;
    }
    o[64] = d2v;
}

// ---------------- per-layer q-table: T[g][j] = fe(g/128) @ W1c + b1 ----------------
__global__ __launch_bounds__(256) void k_tab(const float* __restrict__ feG,   // [TROWS][68]
                                             const float* __restrict__ W1cp,  // [65][768]
                                             const float* __restrict__ b1p,   // [768]
                                             float* __restrict__ T) {         // [TROWS][648]
    __shared__ float feGs[32 * 68];
    __shared__ float W1s[65 * 36];
    const int tid = threadIdx.x;
    const int g0 = blockIdx.x * 32;
    for (int idx = tid; idx < 32 * 17; idx += 256) {
        int r = idx / 17, c = idx - r * 17;
        int gi = g0 + r;
        float4 v = make_float4(0, 0, 0, 0);
        if (gi < TROWS) v = *(const float4*)(feG + (size_t)gi * 68 + 4 * c);
        *(float4*)&feGs[r * 68 + 4 * c] = v;
    }
    const int gt = tid >> 3, ct = tid & 7;
    for (int jc = 0; jc < TCOLS; jc += 32) {
        __syncthreads();
        for (int idx = tid; idx < 65 * 32; idx += 256) {
            int k = idx >> 5, j = idx & 31;
            W1s[k * 36 + j] = W1cp[(size_t)k * 768 + jc + j];
        }
        __syncthreads();
        int gj = jc + 4 * ct;
        float4 q = *(const float4*)(b1p + gj);
        #pragma unroll 5
        for (int k = 0; k < 65; ++k) {
            float f = feGs[gt * 68 + k];
            float4 w = *(const float4*)&W1s[k * 36 + 4 * ct];
            q = f4fma(f, w, q);
        }
        int g = g0 + gt;
        if (g < TROWS && gj < TCOLS)
            *(float4*)(T + (size_t)g * TCOLS + gj) = q;
    }
}

// ---------------- W1ab prestage, all 5 layers: [5][128][1536] ----------------
__global__ __launch_bounds__(256) void k_w1ab5(const float* __restrict__ eW1,
                                               float* __restrict__ W1ab5) {
    int k = blockIdx.y;
    const float* W1 = eW1 + (size_t)k * 321 * 642;
    float* W1ab = W1ab5 + (size_t)k * 128 * 1536;
    int idx = blockIdx.x * 256 + threadIdx.x;
    if (idx >= 128 * 1536) return;
    int r = idx / 1536;
    int j = idx - r * 1536;
    float v = 0.f;
    if (j < 642) v = W1[(size_t)r * 642 + j];
    else if (j >= 768 && j < 1410) v = W1[(size_t)(128 + r) * 642 + (j - 768)];
    W1ab[idx] = v;
}

// ---------------- padded edge-weight prestage (all 5 layers) ----------------
__global__ __launch_bounds__(256) void k_wpre5(const float* __restrict__ eW1,
                                               const float* __restrict__ eb1,
                                               const float* __restrict__ eW2,
                                               float* __restrict__ W1cp5,   // [5][65][768]
                                               float* __restrict__ b1p5,    // [5][768]
                                               float* __restrict__ W2p5) {  // [5][768][32]
    int k = blockIdx.y;
    const float* W1 = eW1 + (size_t)k * 321 * 642;
    const float* b1 = eb1 + (size_t)k * 642;
    const float* W2 = eW2 + (size_t)k * 642 * 32;
    float* W1cp = W1cp5 + (size_t)k * 65 * 768;
    float* b1p  = b1p5 + (size_t)k * 768;
    float* W2p  = W2p5 + (size_t)k * 768 * 32;
    int idx = blockIdx.x * 256 + threadIdx.x;
    if (idx < 65 * 768) {
        int r = idx / 768, j = idx - r * 768;
        W1cp[idx] = (j < 642) ? W1[(size_t)(256 + r) * 642 + j] : 0.f;
    } else if (idx < 65 * 768 + 768) {
        int j = idx - 65 * 768;
        b1p[j] = (j < 642) ? b1[j] : 0.f;
    } else if (idx < 65 * 768 + 768 + 768 * 32) {
        int t = idx - (65 * 768 + 768);
        int j = t >> 5, c = t & 31;
        W2p[t] = (j < 642) ? W2[(size_t)j * 32 + c] : 0.f;
    }
}

// ---------------- fp32 GEMM: C = act(actA(A)[M][K] @ B[K][N] + bias) ----------------
__global__ __launch_bounds__(256) void k_gemm(const float* __restrict__ A, int lda,
                                              const float* __restrict__ B, int ldb,
                                              const float* __restrict__ bias,
                                              float* __restrict__ C, int ldc,
                                              int M, int N, int K, int siluA, int siluOut) {
    __shared__ float As[32 * 132];
    __shared__ float Bs[32 * 132];
    const int tid = threadIdx.x;
    const int m0 = blockIdx.x * 128, n0 = blockIdx.y * 128;
    const int tm = tid >> 4, tn = tid & 15;

    float4 acc[8][2];
    #pragma unroll
    for (int r = 0; r < 8; ++r) { acc[r][0] = make_float4(0,0,0,0); acc[r][1] = make_float4(0,0,0,0); }

    for (int kc = 0; kc < K; kc += 32) {
        #pragma unroll
        for (int i = 0; i < 4; ++i) {
            int idx = tid + i * 256;
            int m = idx >> 3, kq = idx & 7;
            int gm = m0 + m;
            int cm = (gm < M) ? gm : (M - 1);
            float4 a = *(const float4*)(A + (size_t)cm * lda + kc + 4 * kq);
            if (gm >= M) a = make_float4(0,0,0,0);
            if (siluA) { a.x = silu(a.x); a.y = silu(a.y); a.z = silu(a.z); a.w = silu(a.w); }
            As[(4 * kq + 0) * 132 + m] = a.x;
            As[(4 * kq + 1) * 132 + m] = a.y;
            As[(4 * kq + 2) * 132 + m] = a.z;
            As[(4 * kq + 3) * 132 + m] = a.w;
        }
        #pragma unroll
        for (int i = 0; i < 4; ++i) {
            int idx = tid + i * 256;
            int r = idx >> 5, cq = idx & 31;
            int gn = n0 + 4 * cq;
            float4 b = make_float4(0,0,0,0);
            if (gn < N) b = *(const float4*)(B + (size_t)(kc + r) * ldb + gn);
            *(float4*)&Bs[r * 132 + 4 * cq] = b;
        }
        __syncthreads();
        #pragma unroll 4
        for (int kk = 0; kk < 32; ++kk) {
            float4 a0 = *(const float4*)&As[kk * 132 + 8 * tm];
            float4 a1 = *(const float4*)&As[kk * 132 + 8 * tm + 4];
            float4 b0 = *(const float4*)&Bs[kk * 132 + 4 * tn];
            float4 b1 = *(const float4*)&Bs[kk * 132 + 64 + 4 * tn];
            acc[0][0] = f4fma(a0.x, b0, acc[0][0]); acc[0][1] = f4fma(a0.x, b1, acc[0][1]);
            acc[1][0] = f4fma(a0.y, b0, acc[1][0]); acc[1][1] = f4fma(a0.y, b1, acc[1][1]);
            acc[2][0] = f4fma(a0.z, b0, acc[2][0]); acc[2][1] = f4fma(a0.z, b1, acc[2][1]);
            acc[3][0] = f4fma(a0.w, b0, acc[3][0]); acc[3][1] = f4fma(a0.w, b1, acc[3][1]);
            acc[4][0] = f4fma(a1.x, b0, acc[4][0]); acc[4][1] = f4fma(a1.x, b1, acc[4][1]);
            acc[5][0] = f4fma(a1.y, b0, acc[5][0]); acc[5][1] = f4fma(a1.y, b1, acc[5][1]);
            acc[6][0] = f4fma(a1.z, b0, acc[6][0]); acc[6][1] = f4fma(a1.z, b1, acc[6][1]);
            acc[7][0] = f4fma(a1.w, b0, acc[7][0]); acc[7][1] = f4fma(a1.w, b1, acc[7][1]);
        }
        __syncthreads();
    }

    const int gnl = n0 + 4 * tn, gnh = n0 + 64 + 4 * tn;
    #pragma unroll
    for (int r = 0; r < 8; ++r) {
        int gm = m0 + 8 * tm + r;
        if (gm >= M) continue;
        float4 v0 = acc[r][0], v1 = acc[r][1];
        if (gnl < N) {
            if (bias) { v0.x += bias[gnl+0]; v0.y += bias[gnl+1]; v0.z += bias[gnl+2]; v0.w += bias[gnl+3]; }
            if (siluOut) { v0.x = silu(v0.x); v0.y = silu(v0.y); v0.z = silu(v0.z); v0.w = silu(v0.w); }
            *(float4*)&C[(size_t)gm * ldc + gnl] = v0;
        }
        if (gnh < N) {
            if (bias) { v1.x += bias[gnh+0]; v1.y += bias[gnh+1]; v1.z += bias[gnh+2]; v1.w += bias[gnh+3]; }
            if (siluOut) { v1.x = silu(v1.x); v1.y = silu(v1.y); v1.z = silu(v1.z); v1.w = silu(v1.w); }
            *(float4*)&C[(size_t)gm * ldc + gnh] = v1;
        }
    }
}

// ---------------- fused edge kernel: table-lerp phase-1, Zs phase-2 (i0-sorted edges) ----------------
// 64 edges/block, 128 threads, 11 chunks of 64 cols. Edge metadata is pre-sorted by i0 so
// consecutive edges share T rows (T gathers hit L1). Pab GEMM must write all 1536 cols.
__global__ __launch_bounds__(128) void k_edge(const int* __restrict__ ssiP,
                                              const int* __restrict__ dsiP,
                                              const int* __restrict__ i0P,
                                              const float* __restrict__ frP,
                                              const float* __restrict__ T,     // [TROWS][648]
                                              const float* __restrict__ Pab,   // [N_NODES][1536]
                                              const float* __restrict__ W2p,   // [768][32]
                                              const float* __restrict__ b2,
                                              const float* __restrict__ eng,
                                              const float* __restrict__ enb,
                                              float* __restrict__ S) {
    __shared__ float U[3392];            // Zs[32][68]=2176 | W2s[32][36]=1152; overlay m2s[64][36]
    __shared__ int dsi[EPB], ssi[EPB], i0s[EPB];
    __shared__ float frs[EPB];
    __shared__ float cpar[96];
    float* Zs  = U;
    float* W2s = U + 2176;
    float* m2s = U;

    const int tid = threadIdx.x;
    const int eb = blockIdx.x * EPB;
    const int et = tid & 15, cg = tid >> 4;   // phase-1: edges 4*et.., cols 8*cg..
    const int eg = tid >> 3, cq = tid & 7;    // phase-2: edges 4*eg.., cols 4*cq..

    if (tid < EPB) {
        ssi[tid] = ssiP[eb + tid];
        dsi[tid] = dsiP[eb + tid];
        i0s[tid] = i0P[eb + tid];
        frs[tid] = frP[eb + tid];
    }
    if (tid < 32) cpar[tid] = b2[tid];
    else if (tid < 64) cpar[tid] = eng[tid - 32];
    else if (tid < 96) cpar[tid] = enb[tid - 64];
    __syncthreads();

    int dsr[4], ssr[4], i0r[4];
    float frr[4];
    #pragma unroll
    for (int i = 0; i < 4; ++i) {
        int e = 4 * et + i;
        dsr[i] = dsi[e]; ssr[i] = ssi[e];
        i0r[i] = i0s[e]; frr[i] = frs[e];
    }

    float4 accm[4];
    #pragma unroll
    for (int i = 0; i < 4; ++i) accm[i] = make_float4(0,0,0,0);

    for (int ch = 0; ch < 11; ++ch) {
        const int jc = 64 * ch;
        const int colb = jc + 8 * cg;
        float qa[4][8];
        if (colb < TCOLS) {
            #pragma unroll
            for (int i = 0; i < 4; ++i) {
                const float* t0 = T + (size_t)i0r[i] * TCOLS + colb;
                float4 a0 = *(const float4*)t0;
                float4 a1 = *(const float4*)(t0 + 4);
                float4 b0 = *(const float4*)(t0 + TCOLS);
                float4 b1 = *(const float4*)(t0 + TCOLS + 4);
                const float* pr = Pab + (size_t)dsr[i] * PSTRIDE + colb;
                const float* qr = Pab + (size_t)ssr[i] * PSTRIDE + JP + colb;
                float4 p0 = *(const float4*)pr;
                float4 p1 = *(const float4*)(pr + 4);
                float4 q0 = *(const float4*)qr;
                float4 q1 = *(const float4*)(qr + 4);
                float f = frr[i];
                qa[i][0] = silu(fmaf(f, b0.x - a0.x, a0.x) + p0.x + q0.x);
                qa[i][1] = silu(fmaf(f, b0.y - a0.y, a0.y) + p0.y + q0.y);
                qa[i][2] = silu(fmaf(f, b0.z - a0.z, a0.z) + p0.z + q0.z);
                qa[i][3] = silu(fmaf(f, b0.w - a0.w, a0.w) + p0.w + q0.w);
                qa[i][4] = silu(fmaf(f, b1.x - a1.x, a1.x) + p1.x + q1.x);
                qa[i][5] = silu(fmaf(f, b1.y - a1.y, a1.y) + p1.y + q1.y);
                qa[i][6] = silu(fmaf(f, b1.z - a1.z, a1.z) + p1.z + q1.z);
                qa[i][7] = silu(fmaf(f, b1.w - a1.w, a1.w) + p1.w + q1.w);
            }
        } else {
            #pragma unroll
            for (int i = 0; i < 4; ++i)
                #pragma unroll
                for (int c = 0; c < 8; ++c) qa[i][c] = 0.f;
        }

        // ---- phase 2: 2 passes of 32 j ----
        #pragma unroll
        for (int p = 0; p < 2; ++p) {
            __syncthreads();   // Zs free
            if ((cg >> 2) == p) {
                int jl = 8 * (cg & 3);
                #pragma unroll
                for (int jj = 0; jj < 8; ++jj) {
                    *(float4*)&Zs[(jl + jj) * 68 + 4 * et] =
                        make_float4(qa[0][jj], qa[1][jj], qa[2][jj], qa[3][jj]);
                }
            }
            #pragma unroll
            for (int i = 0; i < 2; ++i) {   // stage W2s rows (jc + 32p + r)
                int idx = tid + i * 128;
                int r = idx >> 3, q = idx & 7;
                *(float4*)&W2s[r * 36 + 4 * q] = *(const float4*)(W2p + (size_t)(jc + 32 * p + r) * 32 + 4 * q);
            }
            __syncthreads();
            #pragma unroll 4
            for (int kk = 0; kk < 32; ++kk) {
                float4 z4 = *(const float4*)&Zs[kk * 68 + 4 * eg];
                float4 w4 = *(const float4*)&W2s[kk * 36 + 4 * cq];
                accm[0] = f4fma(z4.x, w4, accm[0]);
                accm[1] = f4fma(z4.y, w4, accm[1]);
                accm[2] = f4fma(z4.z, w4, accm[2]);
                accm[3] = f4fma(z4.w, w4, accm[3]);
            }
        }
    }

    // ---- epilogue: m2 = silu(accm + b2), LN, scatter ----
    __syncthreads();
    {
        float4 bb2 = *(const float4*)&cpar[4 * cq];
        #pragma unroll
        for (int i = 0; i < 4; ++i) {
            int e = 4 * eg + i;
            m2s[e * 36 + 4 * cq + 0] = silu(accm[i].x + bb2.x);
            m2s[e * 36 + 4 * cq + 1] = silu(accm[i].y + bb2.y);
            m2s[e * 36 + 4 * cq + 2] = silu(accm[i].z + bb2.z);
            m2s[e * 36 + 4 * cq + 3] = silu(accm[i].w + bb2.w);
        }
    }
    __syncthreads();
    if (tid < EPB) {
        float s = 0.f, ss = 0.f;
        float v[32];
        #pragma unroll
        for (int c = 0; c < 32; ++c) {
            float x = m2s[tid * 36 + c];
            v[c] = x; s += x; ss += x * x;
        }
        float mean = s * 0.03125f;
        float var = ss * 0.03125f - mean * mean;
        float rstd = 1.0f / sqrtf(var + EPS);
        int d = dsi[tid];
        float* Sp = S + (size_t)d * 32;
        #pragma unroll
        for (int c = 0; c < 32; ++c) {
            float y = (v[c] - mean) * rstd * cpar[32 + c] + cpar[64 + c];
            atomicAdd(&Sp[c], y);
        }
    }
}

// ---------------- node prep: H0 = [LN(feats) | LN(S/cnt)] ----------------
__global__ __launch_bounds__(128) void k_prep(const float* __restrict__ featsk,
                                              const float* __restrict__ S,
                                              const float* __restrict__ cnt,
                                              const float* __restrict__ nn1g,
                                              const float* __restrict__ nn1b,
                                              const float* __restrict__ eng,
                                              const float* __restrict__ enb,
                                              float* __restrict__ H0) {
    int n = blockIdx.x, tid = threadIdx.x;
    __shared__ float red[4];
    float x = featsk[(size_t)n * 768 + tid];
    float s = wave_sum64(x), ss = wave_sum64(x * x);
    if ((tid & 63) == 0) { red[(tid >> 6) * 2] = s; red[(tid >> 6) * 2 + 1] = ss; }
    __syncthreads();
    float S1 = red[0] + red[2], S2 = red[1] + red[3];
    float mean = S1 * (1.0f / 128.0f);
    float var = S2 * (1.0f / 128.0f) - mean * mean;
    float rstd = 1.0f / sqrtf(var + EPS);
    H0[(size_t)n * 160 + tid] = (x - mean) * rstd * nn1g[tid] + nn1b[tid];
    if (tid < 32) {
        float inv = 1.0f / fmaxf(cnt[n], 1.0f);
        float v = S[(size_t)n * 32 + tid] * inv;
        float s2 = v, q2 = v * v;
        #pragma unroll
        for (int off = 16; off > 0; off >>= 1) {
            s2 += __shfl_xor(s2, off, 64);
            q2 += __shfl_xor(q2, off, 64);
        }
        float m2 = s2 * (1.0f / 32.0f);
        float va = q2 * (1.0f / 32.0f) - m2 * m2;
        float rs = 1.0f / sqrtf(va + EPS);
        H0[(size_t)n * 160 + 128 + tid] = (v - m2) * rs * eng[tid] + enb[tid];
    }
}

// ---------------- LN + residual ----------------
__global__ __launch_bounds__(128) void k_ln_res(const float* __restrict__ H2,
                                                float* __restrict__ feats_all, int k,
                                                const float* __restrict__ g,
                                                const float* __restrict__ b) {
    int n = blockIdx.x, tid = threadIdx.x;
    __shared__ float red[4];
    float x = H2[(size_t)n * 128 + tid];
    float s = wave_sum64(x), ss = wave_sum64(x * x);
    if ((tid & 63) == 0) { red[(tid >> 6) * 2] = s; red[(tid >> 6) * 2 + 1] = ss; }
    __syncthreads();
    float S1 = red[0] + red[2], S2 = red[1] + red[3];
    float mean = S1 * (1.0f / 128.0f);
    float var = S2 * (1.0f / 128.0f) - mean * mean;
    float rstd = 1.0f / sqrtf(var + EPS);
    float v = (x - mean) * rstd * g[tid] + b[tid];
    float f = feats_all[(size_t)n * 768 + k * 128 + tid];
    feats_all[(size_t)n * 768 + (k + 1) * 128 + tid] = f + v;
}

// ---------------- graph pooling (batch sorted -> run-length accum) ----------------
__global__ __launch_bounds__(256) void k_pool(const float* __restrict__ F,
                                              const int* __restrict__ batch,
                                              float* __restrict__ G,
                                              float* __restrict__ cntg) {
    __shared__ int bL[32];
    int b0 = blockIdx.x * 32;
    int tid = threadIdx.x;
    int nmax = min(32, N_NODES - b0);
    if (nmax <= 0) return;
    if (tid < nmax) bL[tid] = batch[b0 + tid];
    __syncthreads();
    float accv = 0.f;
    int cur = -1;
    for (int i = 0; i < nmax; ++i) {
        int g = bL[i];
        if (g != cur) {
            if (cur >= 0) atomicAdd(&G[(size_t)cur * 256 + tid], accv);
            cur = g; accv = 0.f;
        }
        accv += F[(size_t)(b0 + i) * 256 + tid];
    }
    if (cur >= 0) atomicAdd(&G[(size_t)cur * 256 + tid], accv);
    if (tid == 0)
        for (int i = 0; i < nmax; ++i) atomicAdd(&cntg[bL[i]], 1.0f);
}

// ---------------- per-graph MLP head ----------------
__global__ __launch_bounds__(256) void k_graph(const float* __restrict__ G,
                                               const float* __restrict__ cntg,
                                               const float* __restrict__ g1W,
                                               const float* __restrict__ g1b,
                                               const float* __restrict__ g2W,
                                               const float* __restrict__ g2b,
                                               const float* __restrict__ g3W,
                                               const float* __restrict__ g3b,
                                               float* __restrict__ out) {
    __shared__ float X[256], Y[256], red[4];
    int g = blockIdx.x, tid = threadIdx.x;
    float inv = 1.0f / fmaxf(cntg[g], 1.0f);
    X[tid] = G[(size_t)g * 256 + tid] * inv;
    __syncthreads();
    float a = g1b[tid];
    for (int j = 0; j < 256; ++j) a = fmaf(X[j], g1W[(size_t)j * 256 + tid], a);
    Y[tid] = silu(a);
    __syncthreads();
    a = g2b[tid];
    for (int j = 0; j < 256; ++j) a = fmaf(Y[j], g2W[(size_t)j * 256 + tid], a);
    float z = silu(a);
    float p = z * g3W[tid];
    p = wave_sum64(p);
    if ((tid & 63) == 0) red[tid >> 6] = p;
    __syncthreads();
    if (tid == 0) out[g] = red[0] + red[1] + red[2] + red[3] + g3b[0];
}

extern "C" void kernel_launch(void* const* d_in, const int* in_sizes, int n_in,
                              void* d_out, int out_size, void* d_ws, size_t ws_size,
                              hipStream_t stream) {
    const int*   atomids = (const int*)d_in[0];
    const float* coords  = (const float*)d_in[1];
    const int*   eidx    = (const int*)d_in[2];
    const int*   batch   = (const int*)d_in[3];
    const float* emb_w   = (const float*)d_in[4];
    const float* eW1     = (const float*)d_in[5];
    const float* eb1     = (const float*)d_in[6];
    const float* eW2     = (const float*)d_in[7];
    const float* eb2     = (const float*)d_in[8];
    const float* en_g    = (const float*)d_in[9];
    const float* en_b    = (const float*)d_in[10];
    const float* nn1_g   = (const float*)d_in[11];
    const float* nn1_b   = (const float*)d_in[12];
    const float* nW1     = (const float*)d_in[13];
    const float* nb1     = (const float*)d_in[14];
    const float* nW2     = (const float*)d_in[15];
    const float* nb2     = (const float*)d_in[16];
    const float* nn2_g   = (const float*)d_in[17];
    const float* nn2_b   = (const float*)d_in[18];
    const float* f1W     = (const float*)d_in[19];
    const float* f1b     = (const float*)d_in[20];
    const float* f2W     = (const float*)d_in[21];
    const float* f2b     = (const float*)d_in[22];
    const float* f3W     = (const float*)d_in[23];
    const float* f3b     = (const float*)d_in[24];
    const float* g1W     = (const float*)d_in[25];
    const float* g1b     = (const float*)d_in[26];
    const float* g2W     = (const float*)d_in[27];
    const float* g2b     = (const float*)d_in[28];
    const float* g3W     = (const float*)d_in[29];
    const float* g3b     = (const float*)d_in[30];
    float* out = (float*)d_out;

    float* ws = (float*)d_ws;
    float* feats_all = ws;                        // [10000][768]
    float* d2g   = ws + 7680000;                  // [160000]
    float* Pab   = ws + 7840000;                  // [10000][1536]
    float* S     = ws + 23200000;                 // [10000][32]
    float* cnt   = ws + 23520000;                 // [10000]
    float* W1ab5 = ws + 23530000;                 // [5][128][1536]
    float* W1cp5 = ws + 24513040;                 // [5][65][768]
    float* b1p5  = ws + 24762640;                 // [5][768]
    float* W2p5  = ws + 24766480;                 // [5][768][32]
    float* feG   = ws + 24889360;                 // [12289][68]
    float* T     = ws + 25725012;                 // [12289][648]
    float* G     = ws + 33688284;                 // [64][256]
    float* cntg  = ws + 33704668;                 // [64]
    // edge sort scratch
    int*   histI = (int*)(ws + 33704736);         // [12304]
    int*   offs  = (int*)(ws + 33717040);         // [12304]
    int*   cursor= (int*)(ws + 33729344);         // [12304]
    int*   ssiP  = (int*)(ws + 33741648);         // [160000]
    int*   dsiP  = (int*)(ws + 33901648);         // [160000]
    int*   i0P   = (int*)(ws + 34061648);         // [160000]
    float* frP   = ws + 34221648;                 // [160000]  (end ~34.38M floats = 137.5 MB)
    // node-phase temporaries overlay Pab (dead between phases)
    float* H0 = Pab;                              // [10000][160]
    float* H1 = Pab + 1600000;                    // [10000][256]
    float* H2 = Pab + 4160000;                    // [10000][128]
    float* F1 = Pab;                              // [10000][256]
    float* F2 = Pab + 2560000;                    // [10000][256]
    float* F3 = Pab + 5120000;                    // [10000][256]

    k_embed<<<N_NODES, 128, 0, stream>>>(atomids, emb_w, feats_all);
    k_d2<<<(N_EDGES + 255) / 256, 256, 0, stream>>>(coords, eidx, d2g);
    hipMemsetAsync(cnt, 0, 10000 * sizeof(float), stream);
    k_cnt<<<(N_EDGES + 255) / 256, 256, 0, stream>>>(eidx, cnt);
    // counting sort of edges by i0 (once; d2 is layer-invariant)
    hipMemsetAsync(histI, 0, 12304 * sizeof(int), stream);
    k_hist<<<(N_EDGES + 255) / 256, 256, 0, stream>>>(d2g, histI);
    k_scan<<<1, 256, 0, stream>>>(histI, offs);
    k_copyi<<<(TROWS + 255) / 256, 256, 0, stream>>>(offs, cursor);
    k_scatter<<<(N_EDGES + 255) / 256, 256, 0, stream>>>(eidx, d2g, cursor,
                                                         ssiP, dsiP, i0P, frP);
    k_feg<<<(TROWS + 255) / 256, 256, 0, stream>>>(feG);
    k_w1ab5<<<dim3(768, 5), 256, 0, stream>>>(eW1, W1ab5);
    k_wpre5<<<dim3(294, 5), 256, 0, stream>>>(eW1, eb1, eW2, W1cp5, b1p5, W2p5);

    for (int k = 0; k < NK; ++k) {
        const float* eb2k = eb2 + (size_t)k * 32;
        const float* engk = en_g + (size_t)k * 32;
        const float* enbk = en_b + (size_t)k * 32;
        const float* nn1gk = nn1_g + (size_t)k * 128;
        const float* nn1bk = nn1_b + (size_t)k * 128;
        const float* nW1k = nW1 + (size_t)k * 160 * 256;
        const float* nb1k = nb1 + (size_t)k * 256;
        const float* nW2k = nW2 + (size_t)k * 256 * 128;
        const float* nb2k = nb2 + (size_t)k * 128;
        const float* nn2gk = nn2_g + (size_t)k * 128;
        const float* nn2bk = nn2_b + (size_t)k * 128;

        k_tab<<<(TROWS + 31) / 32, 256, 0, stream>>>(feG,
                                                     W1cp5 + (size_t)k * 65 * 768,
                                                     b1p5 + (size_t)k * 768, T);
        // MUST write all 1536 Pab columns (k_edge reads zero-padding up to col 1471)
        k_gemm<<<dim3(79, 12), 256, 0, stream>>>(feats_all + k * 128, 768,
                                                 W1ab5 + (size_t)k * 128 * 1536, 1536,
                                                 nullptr, Pab, 1536, N_NODES, 1536, 128, 0, 0);
        hipMemsetAsync(S, 0, (size_t)320000 * sizeof(float), stream);
        k_edge<<<N_EDGES / EPB, 128, 0, stream>>>(ssiP, dsiP, i0P, frP, T, Pab,
                                                  W2p5 + (size_t)k * 768 * 32,
                                                  eb2k, engk, enbk, S);
        k_prep<<<N_NODES, 128, 0, stream>>>(feats_all + k * 128, S, cnt,
                                            nn1gk, nn1bk, engk, enbk, H0);
        k_gemm<<<dim3(79, 2), 256, 0, stream>>>(H0, 160, nW1k, 256, nb1k, H1, 256,
                                                N_NODES, 256, 160, 0, 1);
        k_gemm<<<dim3(79, 1), 256, 0, stream>>>(H1, 256, nW2k, 128, nb2k, H2, 128,
                                                N_NODES, 128, 256, 0, 0);
        k_ln_res<<<N_NODES, 128, 0, stream>>>(H2, feats_all, k, nn2gk, nn2bk);
    }

    // final node MLP (F1/F2/F3 overlay Pab)
    k_gemm<<<dim3(79, 2), 256, 0, stream>>>(feats_all, 768, f1W, 256, f1b, F1, 256,
                                            N_NODES, 256, 768, 1, 1);
    k_gemm<<<dim3(79, 2), 256, 0, stream>>>(F1, 256, f2W, 256, f2b, F2, 256,
                                            N_NODES, 256, 256, 0, 1);
    k_gemm<<<dim3(79, 2), 256, 0, stream>>>(F2, 256, f3W, 256, f3b, F3, 256,
                                            N_NODES, 256, 256, 0, 1);

    hipMemsetAsync(G, 0, (size_t)(16384 + 64) * sizeof(float), stream);
    k_pool<<<313, 256, 0, stream>>>(F3, batch, G, cntg);
    k_graph<<<N_GRAPHS, 256, 0, stream>>>(G, cntg, g1W, g1b, g2W, g2b, g3W, g3b, out);
}

// Round 12
// 3672.981 us; speedup vs baseline: 2.3042x; 1.0021x over previous
//
#include <hip/hip_runtime.h>
#include <hip/hip_bf16.h>

#define N_NODES 10000
#define N_EDGES 160000
#define N_GRAPHS 64
#define NK 5
#define EPS 1e-5f
#define EPB 64           // edges per block (256 threads)
#define JP 648           // packed width for Pab halves
#define PSTRIDE 1296     // Pab row stride: [Pa 648 | Pb 648]
#define TCOLS 648        // table row width (642 -> 648)
#define TROWS 12289      // d2 grid [0,96], h=1/128
#define IMAX 12287

__device__ __forceinline__ float silu(float x) { return x / (1.0f + __expf(-x)); }
__device__ __forceinline__ float4 f4fma(float s, float4 w, float4 a) {
    a.x = fmaf(s, w.x, a.x); a.y = fmaf(s, w.y, a.y);
    a.z = fmaf(s, w.z, a.z); a.w = fmaf(s, w.w, a.w);
    return a;
}
__device__ __forceinline__ float wave_sum64(float v) {
    #pragma unroll
    for (int off = 32; off > 0; off >>= 1) v += __shfl_xor(v, off, 64);
    return v;
}

// ---------------- embedding ----------------
__global__ __launch_bounds__(128) void k_embed(const int* __restrict__ atomids,
                                               const float* __restrict__ emb_w,
                                               float* __restrict__ feats_all) {
    int n = blockIdx.x, tid = threadIdx.x;
    feats_all[(size_t)n * 768 + tid] = emb_w[(size_t)atomids[n] * 128 + tid];
}

// ---------------- per-edge squared distance ----------------
__global__ __launch_bounds__(256) void k_d2(const float* __restrict__ coords,
                                            const int* __restrict__ eidx,
                                            float* __restrict__ d2g) {
    int e = blockIdx.x * 256 + threadIdx.x;
    if (e >= N_EDGES) return;
    int s = eidx[e], d = eidx[N_EDGES + e];
    float dx = coords[s * 3 + 0] - coords[d * 3 + 0];
    float dy = coords[s * 3 + 1] - coords[d * 3 + 1];
    float dz = coords[s * 3 + 2] - coords[d * 3 + 2];
    d2g[e] = dx * dx + dy * dy + dz * dz;
}

// ---------------- in-degree (layer-invariant) ----------------
__global__ __launch_bounds__(256) void k_cnt(const int* __restrict__ eidx,
                                             float* __restrict__ cnt) {
    int e = blockIdx.x * 256 + threadIdx.x;
    if (e >= N_EDGES) return;
    atomicAdd(&cnt[eidx[N_EDGES + e]], 1.0f);
}

// ---------------- counting sort of edges by i0 (T-row index) ----------------
__global__ __launch_bounds__(256) void k_hist(const float* __restrict__ d2g,
                                              int* __restrict__ hist) {
    int e = blockIdx.x * 256 + threadIdx.x;
    if (e >= N_EDGES) return;
    int i0 = (int)(d2g[e] * 128.0f);
    if (i0 > IMAX) i0 = IMAX;
    atomicAdd(&hist[i0], 1);
}

__global__ __launch_bounds__(256) void k_scan(const int* __restrict__ hist,
                                              int* __restrict__ offs) {
    __shared__ int buf[256];
    __shared__ int carryS;
    int tid = threadIdx.x;
    if (tid == 0) carryS = 0;
    __syncthreads();
    for (int base = 0; base < TROWS; base += 256) {
        int v = (base + tid < TROWS) ? hist[base + tid] : 0;
        buf[tid] = v;
        __syncthreads();
        for (int off = 1; off < 256; off <<= 1) {
            int t = (tid >= off) ? buf[tid - off] : 0;
            __syncthreads();
            buf[tid] += t;
            __syncthreads();
        }
        if (base + tid < TROWS) offs[base + tid] = carryS + buf[tid] - v;  // exclusive
        __syncthreads();
        if (tid == 0) carryS += buf[255];
        __syncthreads();
    }
}

__global__ __launch_bounds__(256) void k_copyi(const int* __restrict__ a,
                                               int* __restrict__ b) {
    int i = blockIdx.x * 256 + threadIdx.x;
    if (i < TROWS) b[i] = a[i];
}

__global__ __launch_bounds__(256) void k_scatter(const int* __restrict__ eidx,
                                                 const float* __restrict__ d2g,
                                                 int* __restrict__ cursor,
                                                 int* __restrict__ ssiP,
                                                 int* __restrict__ dsiP,
                                                 int* __restrict__ i0P,
                                                 float* __restrict__ frP) {
    int e = blockIdx.x * 256 + threadIdx.x;
    if (e >= N_EDGES) return;
    float t = d2g[e] * 128.0f;
    int i0 = (int)t;
    if (i0 > IMAX) i0 = IMAX;
    float fr = t - (float)i0;
    int pos = atomicAdd(&cursor[i0], 1);
    ssiP[pos] = eidx[e];
    dsiP[pos] = eidx[N_EDGES + e];
    i0P[pos] = i0;
    frP[pos] = fr;
}

// ---------------- fourier features on the d2 GRID (once) ----------------
__global__ __launch_bounds__(256) void k_feg(float* __restrict__ feG) {  // [TROWS][68]
    int g = blockIdx.x * 256 + threadIdx.x;
    if (g >= TROWS) return;
    float d2v = (float)g * 0.0078125f;   // g / 128, exact
    float* o = feG + (size_t)g * 68;
    float sc = 1.0f;
    #pragma unroll
    for (int i = 0; i < 32; ++i) {
        float x = d2v * sc;
        o[i] = sinf(x);
        o[32 + i] = cosf(x);
        sc *= 0.5f;
    }
    o[64] = d2v;
}

// ---------------- per-layer q-table: T[g][j] = fe(g/128) @ W1c + b1 ----------------
__global__ __launch_bounds__(256) void k_tab(const float* __restrict__ feG,   // [TROWS][68]
                                             const float* __restrict__ W1cp,  // [65][768]
                                             const float* __restrict__ b1p,   // [768]
                                             float* __restrict__ T) {         // [TROWS][648]
    __shared__ float feGs[32 * 68];
    __shared__ float W1s[65 * 36];
    const int tid = threadIdx.x;
    const int g0 = blockIdx.x * 32;
    for (int idx = tid; idx < 32 * 17; idx += 256) {
        int r = idx / 17, c = idx - r * 17;
        int gi = g0 + r;
        float4 v = make_float4(0, 0, 0, 0);
        if (gi < TROWS) v = *(const float4*)(feG + (size_t)gi * 68 + 4 * c);
        *(float4*)&feGs[r * 68 + 4 * c] = v;
    }
    const int gt = tid >> 3, ct = tid & 7;
    for (int jc = 0; jc < TCOLS; jc += 32) {
        __syncthreads();
        for (int idx = tid; idx < 65 * 32; idx += 256) {
            int k = idx >> 5, j = idx & 31;
            W1s[k * 36 + j] = W1cp[(size_t)k * 768 + jc + j];
        }
        __syncthreads();
        int gj = jc + 4 * ct;
        float4 q = *(const float4*)(b1p + gj);
        #pragma unroll 5
        for (int k = 0; k < 65; ++k) {
            float f = feGs[gt * 68 + k];
            float4 w = *(const float4*)&W1s[k * 36 + 4 * ct];
            q = f4fma(f, w, q);
        }
        int g = g0 + gt;
        if (g < TROWS && gj < TCOLS)
            *(float4*)(T + (size_t)g * TCOLS + gj) = q;
    }
}

// ---------------- W1ab prestage, all 5 layers: [5][128][1296] = [W1a|0|W1b|0] packed ----------------
__global__ __launch_bounds__(256) void k_w1ab5(const float* __restrict__ eW1,
                                               float* __restrict__ W1ab5) {
    int k = blockIdx.y;
    const float* W1 = eW1 + (size_t)k * 321 * 642;
    float* W1ab = W1ab5 + (size_t)k * 128 * 1296;
    int idx = blockIdx.x * 256 + threadIdx.x;
    if (idx >= 128 * 1296) return;
    int r = idx / 1296;
    int j = idx - r * 1296;
    float v = 0.f;
    if (j < 642) v = W1[(size_t)r * 642 + j];
    else if (j >= 648 && j < 1290) v = W1[(size_t)(128 + r) * 642 + (j - 648)];
    W1ab[idx] = v;
}

// ---------------- padded edge-weight prestage (all 5 layers) ----------------
__global__ __launch_bounds__(256) void k_wpre5(const float* __restrict__ eW1,
                                               const float* __restrict__ eb1,
                                               const float* __restrict__ eW2,
                                               float* __restrict__ W1cp5,   // [5][65][768]
                                               float* __restrict__ b1p5,    // [5][768]
                                               float* __restrict__ W2p5) {  // [5][768][32]
    int k = blockIdx.y;
    const float* W1 = eW1 + (size_t)k * 321 * 642;
    const float* b1 = eb1 + (size_t)k * 642;
    const float* W2 = eW2 + (size_t)k * 642 * 32;
    float* W1cp = W1cp5 + (size_t)k * 65 * 768;
    float* b1p  = b1p5 + (size_t)k * 768;
    float* W2p  = W2p5 + (size_t)k * 768 * 32;
    int idx = blockIdx.x * 256 + threadIdx.x;
    if (idx < 65 * 768) {
        int r = idx / 768, j = idx - r * 768;
        W1cp[idx] = (j < 642) ? W1[(size_t)(256 + r) * 642 + j] : 0.f;
    } else if (idx < 65 * 768 + 768) {
        int j = idx - 65 * 768;
        b1p[j] = (j < 642) ? b1[j] : 0.f;
    } else if (idx < 65 * 768 + 768 + 768 * 32) {
        int t = idx - (65 * 768 + 768);
        int j = t >> 5, c = t & 31;
        W2p[t] = (j < 642) ? W2[(size_t)j * 32 + c] : 0.f;
    }
}

// ---------------- fp32 GEMM: C = act(actA(A)[M][K] @ B[K][N] + bias) ----------------
__global__ __launch_bounds__(256) void k_gemm(const float* __restrict__ A, int lda,
                                              const float* __restrict__ B, int ldb,
                                              const float* __restrict__ bias,
                                              float* __restrict__ C, int ldc,
                                              int M, int N, int K, int siluA, int siluOut) {
    __shared__ float As[32 * 132];
    __shared__ float Bs[32 * 132];
    const int tid = threadIdx.x;
    const int m0 = blockIdx.x * 128, n0 = blockIdx.y * 128;
    const int tm = tid >> 4, tn = tid & 15;

    float4 acc[8][2];
    #pragma unroll
    for (int r = 0; r < 8; ++r) { acc[r][0] = make_float4(0,0,0,0); acc[r][1] = make_float4(0,0,0,0); }

    for (int kc = 0; kc < K; kc += 32) {
        #pragma unroll
        for (int i = 0; i < 4; ++i) {
            int idx = tid + i * 256;
            int m = idx >> 3, kq = idx & 7;
            int gm = m0 + m;
            int cm = (gm < M) ? gm : (M - 1);
            float4 a = *(const float4*)(A + (size_t)cm * lda + kc + 4 * kq);
            if (gm >= M) a = make_float4(0,0,0,0);
            if (siluA) { a.x = silu(a.x); a.y = silu(a.y); a.z = silu(a.z); a.w = silu(a.w); }
            As[(4 * kq + 0) * 132 + m] = a.x;
            As[(4 * kq + 1) * 132 + m] = a.y;
            As[(4 * kq + 2) * 132 + m] = a.z;
            As[(4 * kq + 3) * 132 + m] = a.w;
        }
        #pragma unroll
        for (int i = 0; i < 4; ++i) {
            int idx = tid + i * 256;
            int r = idx >> 5, cq = idx & 31;
            int gn = n0 + 4 * cq;
            float4 b = make_float4(0,0,0,0);
            if (gn < N) b = *(const float4*)(B + (size_t)(kc + r) * ldb + gn);
            *(float4*)&Bs[r * 132 + 4 * cq] = b;
        }
        __syncthreads();
        #pragma unroll 4
        for (int kk = 0; kk < 32; ++kk) {
            float4 a0 = *(const float4*)&As[kk * 132 + 8 * tm];
            float4 a1 = *(const float4*)&As[kk * 132 + 8 * tm + 4];
            float4 b0 = *(const float4*)&Bs[kk * 132 + 4 * tn];
            float4 b1 = *(const float4*)&Bs[kk * 132 + 64 + 4 * tn];
            acc[0][0] = f4fma(a0.x, b0, acc[0][0]); acc[0][1] = f4fma(a0.x, b1, acc[0][1]);
            acc[1][0] = f4fma(a0.y, b0, acc[1][0]); acc[1][1] = f4fma(a0.y, b1, acc[1][1]);
            acc[2][0] = f4fma(a0.z, b0, acc[2][0]); acc[2][1] = f4fma(a0.z, b1, acc[2][1]);
            acc[3][0] = f4fma(a0.w, b0, acc[3][0]); acc[3][1] = f4fma(a0.w, b1, acc[3][1]);
            acc[4][0] = f4fma(a1.x, b0, acc[4][0]); acc[4][1] = f4fma(a1.x, b1, acc[4][1]);
            acc[5][0] = f4fma(a1.y, b0, acc[5][0]); acc[5][1] = f4fma(a1.y, b1, acc[5][1]);
            acc[6][0] = f4fma(a1.z, b0, acc[6][0]); acc[6][1] = f4fma(a1.z, b1, acc[6][1]);
            acc[7][0] = f4fma(a1.w, b0, acc[7][0]); acc[7][1] = f4fma(a1.w, b1, acc[7][1]);
        }
        __syncthreads();
    }

    const int gnl = n0 + 4 * tn, gnh = n0 + 64 + 4 * tn;
    #pragma unroll
    for (int r = 0; r < 8; ++r) {
        int gm = m0 + 8 * tm + r;
        if (gm >= M) continue;
        float4 v0 = acc[r][0], v1 = acc[r][1];
        if (gnl < N) {
            if (bias) { v0.x += bias[gnl+0]; v0.y += bias[gnl+1]; v0.z += bias[gnl+2]; v0.w += bias[gnl+3]; }
            if (siluOut) { v0.x = silu(v0.x); v0.y = silu(v0.y); v0.z = silu(v0.z); v0.w = silu(v0.w); }
            *(float4*)&C[(size_t)gm * ldc + gnl] = v0;
        }
        if (gnh < N) {
            if (bias) { v1.x += bias[gnh+0]; v1.y += bias[gnh+1]; v1.z += bias[gnh+2]; v1.w += bias[gnh+3]; }
            if (siluOut) { v1.x = silu(v1.x); v1.y = silu(v1.y); v1.z = silu(v1.z); v1.w = silu(v1.w); }
            *(float4*)&C[(size_t)gm * ldc + gnh] = v1;
        }
    }
}

// ---------------- fused edge kernel: table-lerp phase-1, Zs phase-2 (i0-sorted, low-VGPR) ----------------
// 64 edges/block, 256 threads, 11 chunks of 64 cols.
// Phase1 (et2=tid&31: 2 edges, cg=tid>>5: 8 cols): q = lerp(T) + Pa[dst] + Pb[src]; z=silu(q).
// Phase2 (e2m=tid&31: 2 edges, cq2=tid>>5: 4 cols): 2 passes of 32 j via Zs; accm = 2 x float4.
// Per-thread live set ~32 floats -> target <=64 VGPR (8 waves/SIMD occupancy).
// Pab GEMM must write all 1296 columns (zero-pad 642..647 / 1290..1295 is load-bearing).
__global__ __launch_bounds__(256) void k_edge(const int* __restrict__ ssiP,
                                              const int* __restrict__ dsiP,
                                              const int* __restrict__ i0P,
                                              const float* __restrict__ frP,
                                              const float* __restrict__ T,     // [TROWS][648]
                                              const float* __restrict__ Pab,   // [N_NODES][1296]
                                              const float* __restrict__ W2p,   // [768][32]
                                              const float* __restrict__ b2,
                                              const float* __restrict__ eng,
                                              const float* __restrict__ enb,
                                              float* __restrict__ S) {
    __shared__ float U[3392];            // Zs[32][70]=2240 | W2s[32][36]=1152; overlay m2s[64][36]
    __shared__ int dsi[EPB], ssi[EPB], i0s[EPB];
    __shared__ float frs[EPB];
    __shared__ float cpar[96];
    float* Zs  = U;
    float* W2s = U + 2240;
    float* m2s = U;

    const int tid = threadIdx.x;
    const int eb = blockIdx.x * EPB;
    const int et2 = tid & 31, cg = tid >> 5;   // phase-1: edges 2*et2.., cols 8*cg..
    const int e2m = tid & 31, cq2 = tid >> 5;  // phase-2: edges 2*e2m.., cols 4*cq2..

    if (tid < EPB) {
        ssi[tid] = ssiP[eb + tid];
        dsi[tid] = dsiP[eb + tid];
        i0s[tid] = i0P[eb + tid];
        frs[tid] = frP[eb + tid];
    }
    if (tid < 32) cpar[tid] = b2[tid];
    else if (tid < 64) cpar[tid] = eng[tid - 32];
    else if (tid < 96) cpar[tid] = enb[tid - 64];
    __syncthreads();

    int dsr[2], ssr[2], i0r[2];
    float frr[2];
    #pragma unroll
    for (int i = 0; i < 2; ++i) {
        int e = 2 * et2 + i;
        dsr[i] = dsi[e]; ssr[i] = ssi[e];
        i0r[i] = i0s[e]; frr[i] = frs[e];
    }

    float4 accm[2];
    accm[0] = make_float4(0,0,0,0);
    accm[1] = make_float4(0,0,0,0);

    for (int ch = 0; ch < 11; ++ch) {
        const int jc = 64 * ch;
        const int colb = jc + 8 * cg;
        float qa[2][8];
        if (colb < TCOLS) {
            #pragma unroll
            for (int i = 0; i < 2; ++i) {
                const float* t0 = T + (size_t)i0r[i] * TCOLS + colb;
                float4 a0 = *(const float4*)t0;
                float4 a1 = *(const float4*)(t0 + 4);
                float4 b0 = *(const float4*)(t0 + TCOLS);
                float4 b1 = *(const float4*)(t0 + TCOLS + 4);
                const float* pr = Pab + (size_t)dsr[i] * PSTRIDE + colb;
                const float* qr = Pab + (size_t)ssr[i] * PSTRIDE + JP + colb;
                float4 p0 = *(const float4*)pr;
                float4 p1 = *(const float4*)(pr + 4);
                float4 q0 = *(const float4*)qr;
                float4 q1 = *(const float4*)(qr + 4);
                float f = frr[i];
                qa[i][0] = silu(fmaf(f, b0.x - a0.x, a0.x) + p0.x + q0.x);
                qa[i][1] = silu(fmaf(f, b0.y - a0.y, a0.y) + p0.y + q0.y);
                qa[i][2] = silu(fmaf(f, b0.z - a0.z, a0.z) + p0.z + q0.z);
                qa[i][3] = silu(fmaf(f, b0.w - a0.w, a0.w) + p0.w + q0.w);
                qa[i][4] = silu(fmaf(f, b1.x - a1.x, a1.x) + p1.x + q1.x);
                qa[i][5] = silu(fmaf(f, b1.y - a1.y, a1.y) + p1.y + q1.y);
                qa[i][6] = silu(fmaf(f, b1.z - a1.z, a1.z) + p1.z + q1.z);
                qa[i][7] = silu(fmaf(f, b1.w - a1.w, a1.w) + p1.w + q1.w);
            }
        } else {
            #pragma unroll
            for (int i = 0; i < 2; ++i)
                #pragma unroll
                for (int c = 0; c < 8; ++c) qa[i][c] = 0.f;
        }

        // ---- phase 2: 2 passes of 32 j ----
        #pragma unroll
        for (int p = 0; p < 2; ++p) {
            __syncthreads();   // Zs free (previous pass reads done)
            if ((cg >> 2) == p) {         // writer waves: cg in [4p, 4p+4)
                int jl = 8 * (cg & 3);
                #pragma unroll
                for (int jj = 0; jj < 8; ++jj) {
                    float2 z2;
                    z2.x = qa[0][jj]; z2.y = qa[1][jj];
                    *(float2*)&Zs[(jl + jj) * 70 + 2 * et2] = z2;
                }
            }
            {   // stage W2s rows (jc + 32p + r): 32x32 = 256 float4
                int r = tid >> 3, q = tid & 7;
                *(float4*)&W2s[r * 36 + 4 * q] = *(const float4*)(W2p + (size_t)(jc + 32 * p + r) * 32 + 4 * q);
            }
            __syncthreads();
            #pragma unroll 8
            for (int kk = 0; kk < 32; ++kk) {
                float2 z2 = *(const float2*)&Zs[kk * 70 + 2 * e2m];
                float4 w4 = *(const float4*)&W2s[kk * 36 + 4 * cq2];
                accm[0] = f4fma(z2.x, w4, accm[0]);
                accm[1] = f4fma(z2.y, w4, accm[1]);
            }
        }
    }

    // ---- epilogue: m2 = silu(accm + b2), LN, scatter ----
    __syncthreads();
    {
        float4 bb2 = *(const float4*)&cpar[4 * cq2];
        #pragma unroll
        for (int i = 0; i < 2; ++i) {
            int e = 2 * e2m + i;
            m2s[e * 36 + 4 * cq2 + 0] = silu(accm[i].x + bb2.x);
            m2s[e * 36 + 4 * cq2 + 1] = silu(accm[i].y + bb2.y);
            m2s[e * 36 + 4 * cq2 + 2] = silu(accm[i].z + bb2.z);
            m2s[e * 36 + 4 * cq2 + 3] = silu(accm[i].w + bb2.w);
        }
    }
    __syncthreads();
    if (tid < EPB) {
        float s = 0.f, ss = 0.f;
        float v[32];
        #pragma unroll
        for (int c = 0; c < 32; ++c) {
            float x = m2s[tid * 36 + c];
            v[c] = x; s += x; ss += x * x;
        }
        float mean = s * 0.03125f;
        float var = ss * 0.03125f - mean * mean;
        float rstd = 1.0f / sqrtf(var + EPS);
        int d = dsi[tid];
        float* Sp = S + (size_t)d * 32;
        #pragma unroll
        for (int c = 0; c < 32; ++c) {
            float y = (v[c] - mean) * rstd * cpar[32 + c] + cpar[64 + c];
            atomicAdd(&Sp[c], y);
        }
    }
}

// ---------------- node prep: H0 = [LN(feats) | LN(S/cnt)] ----------------
__global__ __launch_bounds__(128) void k_prep(const float* __restrict__ featsk,
                                              const float* __restrict__ S,
                                              const float* __restrict__ cnt,
                                              const float* __restrict__ nn1g,
                                              const float* __restrict__ nn1b,
                                              const float* __restrict__ eng,
                                              const float* __restrict__ enb,
                                              float* __restrict__ H0) {
    int n = blockIdx.x, tid = threadIdx.x;
    __shared__ float red[4];
    float x = featsk[(size_t)n * 768 + tid];
    float s = wave_sum64(x), ss = wave_sum64(x * x);
    if ((tid & 63) == 0) { red[(tid >> 6) * 2] = s; red[(tid >> 6) * 2 + 1] = ss; }
    __syncthreads();
    float S1 = red[0] + red[2], S2 = red[1] + red[3];
    float mean = S1 * (1.0f / 128.0f);
    float var = S2 * (1.0f / 128.0f) - mean * mean;
    float rstd = 1.0f / sqrtf(var + EPS);
    H0[(size_t)n * 160 + tid] = (x - mean) * rstd * nn1g[tid] + nn1b[tid];
    if (tid < 32) {
        float inv = 1.0f / fmaxf(cnt[n], 1.0f);
        float v = S[(size_t)n * 32 + tid] * inv;
        float s2 = v, q2 = v * v;
        #pragma unroll
        for (int off = 16; off > 0; off >>= 1) {
            s2 += __shfl_xor(s2, off, 64);
            q2 += __shfl_xor(q2, off, 64);
        }
        float m2 = s2 * (1.0f / 32.0f);
        float va = q2 * (1.0f / 32.0f) - m2 * m2;
        float rs = 1.0f / sqrtf(va + EPS);
        H0[(size_t)n * 160 + 128 + tid] = (v - m2) * rs * eng[tid] + enb[tid];
    }
}

// ---------------- LN + residual ----------------
__global__ __launch_bounds__(128) void k_ln_res(const float* __restrict__ H2,
                                                float* __restrict__ feats_all, int k,
                                                const float* __restrict__ g,
                                                const float* __restrict__ b) {
    int n = blockIdx.x, tid = threadIdx.x;
    __shared__ float red[4];
    float x = H2[(size_t)n * 128 + tid];
    float s = wave_sum64(x), ss = wave_sum64(x * x);
    if ((tid & 63) == 0) { red[(tid >> 6) * 2] = s; red[(tid >> 6) * 2 + 1] = ss; }
    __syncthreads();
    float S1 = red[0] + red[2], S2 = red[1] + red[3];
    float mean = S1 * (1.0f / 128.0f);
    float var = S2 * (1.0f / 128.0f) - mean * mean;
    float rstd = 1.0f / sqrtf(var + EPS);
    float v = (x - mean) * rstd * g[tid] + b[tid];
    float f = feats_all[(size_t)n * 768 + k * 128 + tid];
    feats_all[(size_t)n * 768 + (k + 1) * 128 + tid] = f + v;
}

// ---------------- graph pooling (batch sorted -> run-length accum) ----------------
__global__ __launch_bounds__(256) void k_pool(const float* __restrict__ F,
                                              const int* __restrict__ batch,
                                              float* __restrict__ G,
                                              float* __restrict__ cntg) {
    __shared__ int bL[32];
    int b0 = blockIdx.x * 32;
    int tid = threadIdx.x;
    int nmax = min(32, N_NODES - b0);
    if (nmax <= 0) return;
    if (tid < nmax) bL[tid] = batch[b0 + tid];
    __syncthreads();
    float accv = 0.f;
    int cur = -1;
    for (int i = 0; i < nmax; ++i) {
        int g = bL[i];
        if (g != cur) {
            if (cur >= 0) atomicAdd(&G[(size_t)cur * 256 + tid], accv);
            cur = g; accv = 0.f;
        }
        accv += F[(size_t)(b0 + i) * 256 + tid];
    }
    if (cur >= 0) atomicAdd(&G[(size_t)cur * 256 + tid], accv);
    if (tid == 0)
        for (int i = 0; i < nmax; ++i) atomicAdd(&cntg[bL[i]], 1.0f);
}

// ---------------- per-graph MLP head ----------------
__global__ __launch_bounds__(256) void k_graph(const float* __restrict__ G,
                                               const float* __restrict__ cntg,
                                               const float* __restrict__ g1W,
                                               const float* __restrict__ g1b,
                                               const float* __restrict__ g2W,
                                               const float* __restrict__ g2b,
                                               const float* __restrict__ g3W,
                                               const float* __restrict__ g3b,
                                               float* __restrict__ out) {
    __shared__ float X[256], Y[256], red[4];
    int g = blockIdx.x, tid = threadIdx.x;
    float inv = 1.0f / fmaxf(cntg[g], 1.0f);
    X[tid] = G[(size_t)g * 256 + tid] * inv;
    __syncthreads();
    float a = g1b[tid];
    for (int j = 0; j < 256; ++j) a = fmaf(X[j], g1W[(size_t)j * 256 + tid], a);
    Y[tid] = silu(a);
    __syncthreads();
    a = g2b[tid];
    for (int j = 0; j < 256; ++j) a = fmaf(Y[j], g2W[(size_t)j * 256 + tid], a);
    float z = silu(a);
    float p = z * g3W[tid];
    p = wave_sum64(p);
    if ((tid & 63) == 0) red[tid >> 6] = p;
    __syncthreads();
    if (tid == 0) out[g] = red[0] + red[1] + red[2] + red[3] + g3b[0];
}

extern "C" void kernel_launch(void* const* d_in, const int* in_sizes, int n_in,
                              void* d_out, int out_size, void* d_ws, size_t ws_size,
                              hipStream_t stream) {
    const int*   atomids = (const int*)d_in[0];
    const float* coords  = (const float*)d_in[1];
    const int*   eidx    = (const int*)d_in[2];
    const int*   batch   = (const int*)d_in[3];
    const float* emb_w   = (const float*)d_in[4];
    const float* eW1     = (const float*)d_in[5];
    const float* eb1     = (const float*)d_in[6];
    const float* eW2     = (const float*)d_in[7];
    const float* eb2     = (const float*)d_in[8];
    const float* en_g    = (const float*)d_in[9];
    const float* en_b    = (const float*)d_in[10];
    const float* nn1_g   = (const float*)d_in[11];
    const float* nn1_b   = (const float*)d_in[12];
    const float* nW1     = (const float*)d_in[13];
    const float* nb1     = (const float*)d_in[14];
    const float* nW2     = (const float*)d_in[15];
    const float* nb2     = (const float*)d_in[16];
    const float* nn2_g   = (const float*)d_in[17];
    const float* nn2_b   = (const float*)d_in[18];
    const float* f1W     = (const float*)d_in[19];
    const float* f1b     = (const float*)d_in[20];
    const float* f2W     = (const float*)d_in[21];
    const float* f2b     = (const float*)d_in[22];
    const float* f3W     = (const float*)d_in[23];
    const float* f3b     = (const float*)d_in[24];
    const float* g1W     = (const float*)d_in[25];
    const float* g1b     = (const float*)d_in[26];
    const float* g2W     = (const float*)d_in[27];
    const float* g2b     = (const float*)d_in[28];
    const float* g3W     = (const float*)d_in[29];
    const float* g3b     = (const float*)d_in[30];
    float* out = (float*)d_out;

    float* ws = (float*)d_ws;
    float* feats_all = ws;                        // [10000][768]
    float* d2g   = ws + 7680000;                  // [160000]
    float* Pab   = ws + 7840000;                  // [10000][1296]
    float* S     = ws + 20800000;                 // [10000][32]
    float* cnt   = ws + 21120000;                 // [10000]
    float* W1ab5 = ws + 21130000;                 // [5][128][1296]
    float* W1cp5 = ws + 21959440;                 // [5][65][768]
    float* b1p5  = ws + 22209040;                 // [5][768]
    float* W2p5  = ws + 22212880;                 // [5][768][32]
    float* feG   = ws + 22335760;                 // [12289][68]
    float* T     = ws + 23171412;                 // [12289][648]
    float* G     = ws + 31134684;                 // [64][256]
    float* cntg  = ws + 31151068;                 // [64]
    int*   histI = (int*)(ws + 31151132);         // [12304]
    int*   offs  = (int*)(ws + 31163436);         // [12304]
    int*   cursor= (int*)(ws + 31175740);         // [12304]
    int*   ssiP  = (int*)(ws + 31188044);         // [160000]
    int*   dsiP  = (int*)(ws + 31348044);         // [160000]
    int*   i0P   = (int*)(ws + 31508044);         // [160000]
    float* frP   = ws + 31668044;                 // [160000] (end ~31.83M floats = 127.3 MB)
    // node-phase temporaries overlay Pab (dead between phases; 12.96M floats available)
    float* H0 = Pab;                              // [10000][160]
    float* H1 = Pab + 1600000;                    // [10000][256]
    float* H2 = Pab + 4160000;                    // [10000][128]
    float* F1 = Pab;                              // [10000][256]
    float* F2 = Pab + 2560000;                    // [10000][256]
    float* F3 = Pab + 5120000;                    // [10000][256]

    k_embed<<<N_NODES, 128, 0, stream>>>(atomids, emb_w, feats_all);
    k_d2<<<(N_EDGES + 255) / 256, 256, 0, stream>>>(coords, eidx, d2g);
    hipMemsetAsync(cnt, 0, 10000 * sizeof(float), stream);
    k_cnt<<<(N_EDGES + 255) / 256, 256, 0, stream>>>(eidx, cnt);
    hipMemsetAsync(histI, 0, 12304 * sizeof(int), stream);
    k_hist<<<(N_EDGES + 255) / 256, 256, 0, stream>>>(d2g, histI);
    k_scan<<<1, 256, 0, stream>>>(histI, offs);
    k_copyi<<<(TROWS + 255) / 256, 256, 0, stream>>>(offs, cursor);
    k_scatter<<<(N_EDGES + 255) / 256, 256, 0, stream>>>(eidx, d2g, cursor,
                                                         ssiP, dsiP, i0P, frP);
    k_feg<<<(TROWS + 255) / 256, 256, 0, stream>>>(feG);
    k_w1ab5<<<dim3(648, 5), 256, 0, stream>>>(eW1, W1ab5);
    k_wpre5<<<dim3(294, 5), 256, 0, stream>>>(eW1, eb1, eW2, W1cp5, b1p5, W2p5);

    for (int k = 0; k < NK; ++k) {
        const float* eb2k = eb2 + (size_t)k * 32;
        const float* engk = en_g + (size_t)k * 32;
        const float* enbk = en_b + (size_t)k * 32;
        const float* nn1gk = nn1_g + (size_t)k * 128;
        const float* nn1bk = nn1_b + (size_t)k * 128;
        const float* nW1k = nW1 + (size_t)k * 160 * 256;
        const float* nb1k = nb1 + (size_t)k * 256;
        const float* nW2k = nW2 + (size_t)k * 256 * 128;
        const float* nb2k = nb2 + (size_t)k * 128;
        const float* nn2gk = nn2_g + (size_t)k * 128;
        const float* nn2bk = nn2_b + (size_t)k * 128;

        k_tab<<<(TROWS + 31) / 32, 256, 0, stream>>>(feG,
                                                     W1cp5 + (size_t)k * 65 * 768,
                                                     b1p5 + (size_t)k * 768, T);
        // MUST write all 1296 Pab columns (k_edge reads zero-padding up to col 1295)
        k_gemm<<<dim3(79, 11), 256, 0, stream>>>(feats_all + k * 128, 768,
                                                 W1ab5 + (size_t)k * 128 * 1296, 1296,
                                                 nullptr, Pab, 1296, N_NODES, 1296, 128, 0, 0);
        hipMemsetAsync(S, 0, (size_t)320000 * sizeof(float), stream);
        k_edge<<<N_EDGES / EPB, 256, 0, stream>>>(ssiP, dsiP, i0P, frP, T, Pab,
                                                  W2p5 + (size_t)k * 768 * 32,
                                                  eb2k, engk, enbk, S);
        k_prep<<<N_NODES, 128, 0, stream>>>(feats_all + k * 128, S, cnt,
                                            nn1gk, nn1bk, engk, enbk, H0);
        k_gemm<<<dim3(79, 2), 256, 0, stream>>>(H0, 160, nW1k, 256, nb1k, H1, 256,
                                                N_NODES, 256, 160, 0, 1);
        k_gemm<<<dim3(79, 1), 256, 0, stream>>>(H1, 256, nW2k, 128, nb2k, H2, 128,
                                                N_NODES, 128, 256, 0, 0);
        k_ln_res<<<N_NODES, 128, 0, stream>>>(H2, feats_all, k, nn2gk, nn2bk);
    }

    // final node MLP (F1/F2/F3 overlay Pab)
    k_gemm<<<dim3(79, 2), 256, 0, stream>>>(feats_all, 768, f1W, 256, f1b, F1, 256,
                                            N_NODES, 256, 768, 1, 1);
    k_gemm<<<dim3(79, 2), 256, 0, stream>>>(F1, 256, f2W, 256, f2b, F2, 256,
                                            N_NODES, 256, 256, 0, 1);
    k_gemm<<<dim3(79, 2), 256, 0, stream>>>(F2, 256, f3W, 256, f3b, F3, 256,
                                            N_NODES, 256, 256, 0, 1);

    hipMemsetAsync(G, 0, (size_t)(16384 + 64) * sizeof(float), stream);
    k_pool<<<313, 256, 0, stream>>>(F3, batch, G, cntg);
    k_graph<<<N_GRAPHS, 256, 0, stream>>>(G, cntg, g1W, g1b, g2W, g2b, g3W, g3b, out);
}